// Round 1
// 218.491 us; speedup vs baseline: 1.0638x; 1.0638x over previous
//
#include <hip/hip_runtime.h>
#include <hip/hip_bf16.h>

// Sizes (fixed): B=2, S=2048, D=1024, H=16, Hd=64
#define SEQ    2048
#define DMODEL 1024
#define NHEAD  16
#define HDIM   64
#define BATCH  2
#define NTOK   (BATCH * SEQ)           // 4096

#define N_X   (NTOK * DMODEL)
#define N_WQ  (3 * DMODEL * DMODEL)
#define N_BQ  (3 * DMODEL)
#define N_WO  (DMODEL * DMODEL)
#define N_BO  (DMODEL)
#define N_CANON (N_X + N_WQ + N_BQ + N_WO + N_BO)   // 8,392,704

#define NEG_SENT (-1.0e30f)
#define QSCALE 0.1803368801111f        // (1/8) * log2(e)

typedef __attribute__((ext_vector_type(8))) short short8;
typedef __attribute__((ext_vector_type(4))) short short4v;
typedef __attribute__((ext_vector_type(4))) float f32x4;

#define MFMA_BF16(A, B, C) __builtin_amdgcn_mfma_f32_16x16x32_bf16((A), (B), (C), 0, 0, 0)

static __device__ __forceinline__ short8 load8(const __hip_bfloat16* p) {
    return *(const short8*)p;
}

static __device__ __forceinline__ void async16(const void* g, void* l) {
    __builtin_amdgcn_global_load_lds(
        (const __attribute__((address_space(1))) unsigned int*)g,
        (__attribute__((address_space(3))) unsigned int*)l,
        16, 0, 0);
}

// ---------------------------------------------------------------------------
// Kernel 0: dtype detector (confirmed fp32 in round 2; keep for robustness)
// ---------------------------------------------------------------------------
__global__ void detect_kernel(const unsigned short* __restrict__ w, int* flag) {
    int cnt = 0;
    for (int i = threadIdx.x; i < 512; i += 64) {
        const unsigned e = (w[i] >> 7) & 0xFF;
        if (e >= 125) cnt++;
    }
#pragma unroll
    for (int o = 32; o; o >>= 1) cnt += __shfl_down(cnt, o);
    if (threadIdx.x == 0) *flag = (cnt > 8) ? 1 : 0;
}

// ---------------------------------------------------------------------------
// Kernel 0b: canonicalize inputs to bf16: [X | Wqkv | bqkv | Wout | bout]
// ---------------------------------------------------------------------------
__global__ __launch_bounds__(256) void canon_kernel(
    const void* __restrict__ s0, const void* __restrict__ s1,
    const void* __restrict__ s2, const void* __restrict__ s3,
    const void* __restrict__ s4,
    __hip_bfloat16* __restrict__ dst, const int* __restrict__ flag)
{
    const int idx = blockIdx.x * 256 + threadIdx.x;
    if (idx >= N_CANON) return;
    const void* src;
    int off;
    if (idx < N_X)                         { src = s0; off = idx; }
    else if (idx < N_X + N_WQ)             { src = s1; off = idx - N_X; }
    else if (idx < N_X + N_WQ + N_BQ)      { src = s2; off = idx - (N_X + N_WQ); }
    else if (idx < N_X + N_WQ + N_BQ + N_WO){ src = s3; off = idx - (N_X + N_WQ + N_BQ); }
    else                                   { src = s4; off = idx - (N_X + N_WQ + N_BQ + N_WO); }
    const bool isf32 = (*flag != 0);
    const float v = isf32 ? ((const float*)src)[off]
                          : __bfloat162float(((const __hip_bfloat16*)src)[off]);
    dst[idx] = __float2bfloat16(v);
}

// ---------------------------------------------------------------------------
// Kernel 1: QKV GEMM, m97 structure (128x128 tile, global_load_lds w=16).
// ---------------------------------------------------------------------------
__global__ __launch_bounds__(256) void qkv_gemm_kernel(
    const __hip_bfloat16* __restrict__ X,
    const __hip_bfloat16* __restrict__ W,
    const __hip_bfloat16* __restrict__ bias,
    __hip_bfloat16* __restrict__ Qs,
    __hip_bfloat16* __restrict__ Kb,
    __hip_bfloat16* __restrict__ Vt)
{
    constexpr int Kd = DMODEL;
    __shared__ __align__(16) __hip_bfloat16 As[128 * 32];
    __shared__ __align__(16) __hip_bfloat16 Bs[128 * 32];

    const int tid   = threadIdx.x;
    const int lane  = tid & 63;
    const int w     = tid >> 6;
    const int mTile = blockIdx.y * 128;
    const int nTile = blockIdx.x * 128;
    const int wm    = (w >> 1) * 64;
    const int wn    = (w & 1) * 64;
    const int lm    = lane & 15;
    const int lk    = (lane >> 4) * 8;

    f32x4 acc[4][4];
#pragma unroll
    for (int i = 0; i < 4; ++i)
#pragma unroll
        for (int j = 0; j < 4; ++j)
            acc[i][j] = (f32x4){0.f, 0.f, 0.f, 0.f};

    const int r0c = tid >> 2, p0c = tid & 3;
    const int r1c = (tid + 256) >> 2, p1c = tid & 3;

    for (int k0 = 0; k0 < Kd; k0 += 32) {
        __syncthreads();
        async16(&X[(size_t)(mTile + r0c) * Kd + k0 + p0c * 8], (char*)As + tid * 16);
        async16(&X[(size_t)(mTile + r1c) * Kd + k0 + p1c * 8], (char*)As + tid * 16 + 4096);
        async16(&W[(size_t)(nTile + r0c) * Kd + k0 + p0c * 8], (char*)Bs + tid * 16);
        async16(&W[(size_t)(nTile + r1c) * Kd + k0 + p1c * 8], (char*)Bs + tid * 16 + 4096);
        __syncthreads();

        short8 a[4], b[4];
#pragma unroll
        for (int i = 0; i < 4; ++i)
            a[i] = *(const short8*)&As[(wm + i * 16 + lm) * 32 + lk];
#pragma unroll
        for (int j = 0; j < 4; ++j)
            b[j] = *(const short8*)&Bs[(wn + j * 16 + lm) * 32 + lk];
#pragma unroll
        for (int i = 0; i < 4; ++i)
#pragma unroll
            for (int j = 0; j < 4; ++j)
                acc[i][j] = MFMA_BF16(a[i], b[j], acc[i][j]);
    }

    const int r0 = (lane >> 4) * 4;
#pragma unroll
    for (int j = 0; j < 4; ++j) {
        const int n  = nTile + wn + j * 16 + lm;
        const float bv = __bfloat162float(bias[n]);
        const int c = n >> 10;
        const int h = (n >> 6) & 15;
        const int d = n & 63;
#pragma unroll
        for (int i = 0; i < 4; ++i) {
#pragma unroll
            for (int r = 0; r < 4; ++r) {
                const int m  = mTile + wm + i * 16 + r0 + r;
                const int bb = m >> 11;
                const int s  = m & (SEQ - 1);
                const int bh = bb * NHEAD + h;
                const float v = acc[i][j][r] + bv;
                if (c == 0) {
                    Qs[(size_t)(bh * SEQ + s) * HDIM + d] = __float2bfloat16(v * QSCALE);
                } else if (c == 1) {
                    Kb[(size_t)(bh * SEQ + s) * HDIM + d] = __float2bfloat16(v);
                } else {
                    Vt[(size_t)(bh * HDIM + d) * SEQ + s] = __float2bfloat16(v);
                }
            }
        }
    }
}

// ---------------------------------------------------------------------------
// Kernel 2: cooperative causal flash attention, PAIR-BALANCED, 8 waves/WG,
// double-buffered K/V staging with counted vmcnt.
//
// Round-10 change vs round 9 (82 us, MfmaUtil 8.4%, Occupancy 10.7%):
//  - 512 threads = 8 waves per WG; each wave owns 16 q-rows (was 4 waves x
//    32 rows).  Same 256 WGs (1/CU), same 34 chunks/WG, same K/V traffic,
//    but 2 waves/SIMD -> softmax dep-chains overlap the other wave's
//    MFMA/LDS issue (latency was fully exposed at 1 wave/SIMD).
//  - K/V tiles double-buffered: prefetch chunk c+1 (2 global_load_lds per
//    thread) before computing chunk c; s_waitcnt vmcnt(2) (never drained to
//    0 mid-loop, T4) + raw s_barrier.  Removes the per-chunk synchronous
//    vmcnt(0) stage stall (~300-900 cy each) from the critical path.
// Pair balance (round 9): nChunks(qb)=2(qb+1), pair (15-p, p) -> 34 chunks
// for every WG, zero tail.  Heavy block first so light block's K/V L2-warm.
// ---------------------------------------------------------------------------
#define P_PITCH 72
__global__ __launch_bounds__(512, 2) void attn_kernel(
    const __hip_bfloat16* __restrict__ Qs,  // [B,H,S,Hd], pre-scaled
    const __hip_bfloat16* __restrict__ Kb,  // [B,H,S,Hd]
    const __hip_bfloat16* __restrict__ Vt,  // [B,H,Hd,S]
    __hip_bfloat16* __restrict__ O)         // [B*S, D]
{
    __shared__ __align__(16) __hip_bfloat16 Kt[2][64 * 64];
    __shared__ __align__(16) __hip_bfloat16 Vs[2][64 * 64];
    __shared__ __align__(16) __hip_bfloat16 Pall[8][16 * P_PITCH];

    const int tid  = threadIdx.x;
    const int lane = tid & 63;
    const int wv   = tid >> 6;              // 0..7
    const int pr   = blockIdx.x;            // pair index 0..7
    const int bh   = blockIdx.y;

    const int lm  = lane & 15;
    const int q4  = lane >> 4;
    const int lk  = q4 * 8;
    const int swz = (lm & 3) << 4;

    __hip_bfloat16* P = Pall[wv];

    const __hip_bfloat16* Qbh = Qs + (size_t)bh * SEQ * HDIM;
    const __hip_bfloat16* Kbh = Kb + (size_t)bh * SEQ * HDIM;
    const __hip_bfloat16* Vbh = Vt + (size_t)bh * HDIM * SEQ;

    // staging address components: 512 threads, 8 threads x 16B per 128B row
    const int srow = tid >> 3;              // 0..63 (k-row for Kt, d-row for Vs)
    const int scb  = (tid & 7) ^ (srow & 7);   // XOR-swizzled column block

    const int b  = bh >> 4;
    const int hh = bh & 15;

    for (int ph = 0; ph < 2; ++ph) {
        const int qb    = ph ? pr : 15 - pr;   // heavy first, then light
        const int wbase = qb * 128 + wv * 16;  // this wave's 16 q-rows

        short8 qa[2];
#pragma unroll
        for (int h = 0; h < 2; ++h)
            qa[h] = load8(&Qbh[(size_t)(wbase + lm) * HDIM + h * 32 + lk]);

        float m_run = NEG_SENT;
        float l_run = 0.f;
        f32x4 Oacc[4];
#pragma unroll
        for (int t = 0; t < 4; ++t) Oacc[t] = (f32x4){0.f, 0.f, 0.f, 0.f};

        const int nChunks = 2 * (qb + 1);
        int cur = 0;

        // prologue: prefetch chunk 0 into buffer 0 (no wait here; first
        // iteration's vmcnt(2) covers it)
        async16(&Kbh[(size_t)srow * HDIM + scb * 8], (char*)Kt[0] + tid * 16);
        async16(&Vbh[(size_t)srow * SEQ + scb * 8],  (char*)Vs[0] + tid * 16);

        for (int c = 0; c < nChunks; ++c) {
            const int k0 = c * 64;

            if (c + 1 < nChunks) {
                const int k1 = k0 + 64;
                async16(&Kbh[(size_t)(k1 + srow) * HDIM + scb * 8],
                        (char*)Kt[cur ^ 1] + tid * 16);
                async16(&Vbh[(size_t)srow * SEQ + k1 + scb * 8],
                        (char*)Vs[cur ^ 1] + tid * 16);
                // 4 outstanding, keep the 2 newest (chunk c+1) in flight
                asm volatile("s_waitcnt vmcnt(2)" ::: "memory");
            } else {
                asm volatile("s_waitcnt vmcnt(0)" ::: "memory");
            }
            __builtin_amdgcn_s_barrier();          // chunk c tiles visible
            __builtin_amdgcn_sched_barrier(0);     // don't hoist ds_reads above

            if (k0 <= wbase + 15) {   // not fully masked for this wave
                const __hip_bfloat16* Kc = Kt[cur];
                const __hip_bfloat16* Vc = Vs[cur];

                short8 ka[4][2];
#pragma unroll
                for (int t = 0; t < 4; ++t)
#pragma unroll
                    for (int h = 0; h < 2; ++h)
                        ka[t][h] = *(const short8*)&Kc[(t * 16 + lm) * 64 +
                                                       (((h * 4 + q4) ^ (lm & 7)) * 8)];

                f32x4 sc[4];
#pragma unroll
                for (int t = 0; t < 4; ++t) sc[t] = (f32x4){0.f, 0.f, 0.f, 0.f};
#pragma unroll
                for (int t = 0; t < 4; ++t) {
                    sc[t] = MFMA_BF16(ka[t][0], qa[0], sc[t]);
                    sc[t] = MFMA_BF16(ka[t][1], qa[1], sc[t]);
                }

                if (k0 + 63 > wbase) {
                    const int row = wbase + lm;
#pragma unroll
                    for (int t = 0; t < 4; ++t)
#pragma unroll
                        for (int r = 0; r < 4; ++r) {
                            const int key = k0 + t * 16 + q4 * 4 + r;
                            if (key > row) sc[t][r] = NEG_SENT;
                        }
                }

                // online softmax (scores for q-row lm live in this lane)
                float mx = sc[0][0];
#pragma unroll
                for (int t = 0; t < 4; ++t)
#pragma unroll
                    for (int r = 0; r < 4; ++r) mx = fmaxf(mx, sc[t][r]);
                mx = fmaxf(mx, __shfl_xor(mx, 16));
                mx = fmaxf(mx, __shfl_xor(mx, 32));
                const float mn = fmaxf(m_run, mx);
                const float alpha = exp2f(m_run - mn);
                float s = 0.f;
#pragma unroll
                for (int t = 0; t < 4; ++t)
#pragma unroll
                    for (int r = 0; r < 4; ++r) {
                        const float p = exp2f(sc[t][r] - mn);
                        sc[t][r] = p;
                        s += p;
                    }
                s += __shfl_xor(s, 16);
                s += __shfl_xor(s, 32);
                l_run = l_run * alpha + s;
                m_run = mn;

#pragma unroll
                for (int r = 0; r < 4; ++r) {
                    const float av = __shfl(alpha, q4 * 4 + r);
#pragma unroll
                    for (int t = 0; t < 4; ++t) Oacc[t][r] *= av;
                }

#pragma unroll
                for (int t = 0; t < 4; ++t) {
                    short4v pk;
#pragma unroll
                    for (int r = 0; r < 4; ++r)
                        pk[r] = (short)__bfloat16_as_ushort(__float2bfloat16(sc[t][r]));
                    const int col = (t * 16 + q4 * 4) ^ swz;
                    *(short4v*)&P[lm * P_PITCH + col] = pk;
                }

#pragma unroll
                for (int h = 0; h < 2; ++h) {
                    const short8 pa = *(const short8*)&P[lm * P_PITCH + ((h * 32 + lk) ^ swz)];
#pragma unroll
                    for (int t = 0; t < 4; ++t) {
                        const short8 vb = *(const short8*)&Vc[(t * 16 + lm) * 64 +
                                                              (((h * 4 + q4) ^ (lm & 7)) * 8)];
                        Oacc[t] = MFMA_BF16(pa, vb, Oacc[t]);
                    }
                }
            }

            __builtin_amdgcn_s_barrier();   // all waves done reading buf[cur]
            cur ^= 1;
        }

        // --- epilogue for this phase's 16 q-rows per wave ---
#pragma unroll
        for (int r = 0; r < 4; ++r) {
            const float lv = __shfl(l_run, q4 * 4 + r);
            const float inv = 1.0f / lv;
            const size_t m = (size_t)b * SEQ + wbase + q4 * 4 + r;
#pragma unroll
            for (int t = 0; t < 4; ++t)
                O[m * DMODEL + hh * 64 + t * 16 + lm] = __float2bfloat16(Oacc[t][r] * inv);
        }
    }
}

// ---------------------------------------------------------------------------
// Kernel 3: out projection, m97 structure.
// ---------------------------------------------------------------------------
__global__ __launch_bounds__(256) void proj_gemm_kernel(
    const __hip_bfloat16* __restrict__ A,
    const __hip_bfloat16* __restrict__ W,
    const __hip_bfloat16* __restrict__ bias,
    void* __restrict__ outv,
    const int* __restrict__ flag)
{
    constexpr int Kd = DMODEL;
    __shared__ __align__(16) __hip_bfloat16 As[128 * 32];
    __shared__ __align__(16) __hip_bfloat16 Bs[128 * 32];

    const int tid   = threadIdx.x;
    const int lane  = tid & 63;
    const int w     = tid >> 6;
    const int mTile = blockIdx.y * 128;
    const int nTile = blockIdx.x * 128;
    const int wm    = (w >> 1) * 64;
    const int wn    = (w & 1) * 64;
    const int lm    = lane & 15;
    const int lk    = (lane >> 4) * 8;
    const bool f32out = (*flag != 0);

    f32x4 acc[4][4];
#pragma unroll
    for (int i = 0; i < 4; ++i)
#pragma unroll
        for (int j = 0; j < 4; ++j)
            acc[i][j] = (f32x4){0.f, 0.f, 0.f, 0.f};

    const int r0c = tid >> 2, p0c = tid & 3;
    const int r1c = (tid + 256) >> 2, p1c = tid & 3;

    for (int k0 = 0; k0 < Kd; k0 += 32) {
        __syncthreads();
        async16(&A[(size_t)(mTile + r0c) * Kd + k0 + p0c * 8], (char*)As + tid * 16);
        async16(&A[(size_t)(mTile + r1c) * Kd + k0 + p1c * 8], (char*)As + tid * 16 + 4096);
        async16(&W[(size_t)(nTile + r0c) * Kd + k0 + p0c * 8], (char*)Bs + tid * 16);
        async16(&W[(size_t)(nTile + r1c) * Kd + k0 + p1c * 8], (char*)Bs + tid * 16 + 4096);
        __syncthreads();

        short8 a[4], b[4];
#pragma unroll
        for (int i = 0; i < 4; ++i)
            a[i] = *(const short8*)&As[(wm + i * 16 + lm) * 32 + lk];
#pragma unroll
        for (int j = 0; j < 4; ++j)
            b[j] = *(const short8*)&Bs[(wn + j * 16 + lm) * 32 + lk];
#pragma unroll
        for (int i = 0; i < 4; ++i)
#pragma unroll
            for (int j = 0; j < 4; ++j)
                acc[i][j] = MFMA_BF16(a[i], b[j], acc[i][j]);
    }

    const int r0 = (lane >> 4) * 4;
#pragma unroll
    for (int j = 0; j < 4; ++j) {
        const int n = nTile + wn + j * 16 + lm;
        const float bv = __bfloat162float(bias[n]);
#pragma unroll
        for (int i = 0; i < 4; ++i) {
#pragma unroll
            for (int r = 0; r < 4; ++r) {
                const size_t m = mTile + wm + i * 16 + r0 + r;
                const float v = acc[i][j][r] + bv;
                if (f32out) ((float*)outv)[m * DMODEL + n] = v;
                else ((__hip_bfloat16*)outv)[m * DMODEL + n] = __float2bfloat16(v);
            }
        }
    }
}

// ---------------------------------------------------------------------------
extern "C" void kernel_launch(void* const* d_in, const int* in_sizes, int n_in,
                              void* d_out, int out_size, void* d_ws, size_t ws_size,
                              hipStream_t stream) {
    // Workspace layout (bytes): [flag:256][canon bf16][Qs][Kb][Vt][Ao]
    const size_t OFF_CANON = 256;
    const size_t OFF_QS = OFF_CANON + (size_t)N_CANON * 2;
    const size_t OFF_KB = OFF_QS + (size_t)NTOK * DMODEL * 2;
    const size_t OFF_VT = OFF_KB + (size_t)NTOK * DMODEL * 2;
    const size_t OFF_AO = OFF_VT + (size_t)NTOK * DMODEL * 2;

    char* wsb = (char*)d_ws;
    int* flag = (int*)wsb;
    __hip_bfloat16* canon = (__hip_bfloat16*)(wsb + OFF_CANON);
    __hip_bfloat16* Xc = canon;
    __hip_bfloat16* Wq = Xc + N_X;
    __hip_bfloat16* Bq = Wq + N_WQ;
    __hip_bfloat16* Wo = Bq + N_BQ;
    __hip_bfloat16* Bo = Wo + N_WO;
    __hip_bfloat16* Qs = (__hip_bfloat16*)(wsb + OFF_QS);
    __hip_bfloat16* Kb = (__hip_bfloat16*)(wsb + OFF_KB);
    __hip_bfloat16* Vt = (__hip_bfloat16*)(wsb + OFF_VT);
    __hip_bfloat16* Ao = (__hip_bfloat16*)(wsb + OFF_AO);

    // 0) dtype detect + canonicalize
    detect_kernel<<<1, 64, 0, stream>>>((const unsigned short*)d_in[1], flag);
    canon_kernel<<<(N_CANON + 255) / 256, 256, 0, stream>>>(
        d_in[0], d_in[1], d_in[2], d_in[3], d_in[4], canon, flag);

    // 1) QKV GEMM
    {
        dim3 grid(3 * DMODEL / 128, NTOK / 128);
        qkv_gemm_kernel<<<grid, 256, 0, stream>>>(Xc, Wq, Bq, Qs, Kb, Vt);
    }
    // 2) Attention: pair-balanced cooperative blocks, grid (8, B*H) = 256 WGs,
    //    8 waves each, double-buffered K/V staging
    {
        dim3 grid(8, BATCH * NHEAD);
        attn_kernel<<<grid, 512, 0, stream>>>(Qs, Kb, Vt, Ao);
    }
    // 3) Out projection
    {
        dim3 grid(DMODEL / 128, NTOK / 128);
        proj_gemm_kernel<<<grid, 256, 0, stream>>>(Ao, Wo, Bo, d_out, flag);
    }
}

// Round 2
// 212.862 us; speedup vs baseline: 1.0919x; 1.0264x over previous
//
#include <hip/hip_runtime.h>
#include <hip/hip_bf16.h>

// Sizes (fixed): B=2, S=2048, D=1024, H=16, Hd=64
#define SEQ    2048
#define DMODEL 1024
#define NHEAD  16
#define HDIM   64
#define BATCH  2
#define NTOK   (BATCH * SEQ)           // 4096

#define N_X   (NTOK * DMODEL)
#define N_WQ  (3 * DMODEL * DMODEL)
#define N_BQ  (3 * DMODEL)
#define N_WO  (DMODEL * DMODEL)
#define N_BO  (DMODEL)
#define N_CANON (N_X + N_WQ + N_BQ + N_WO + N_BO)   // 8,392,704

#define NEG_SENT (-1.0e30f)
#define QSCALE 0.1803368801111f        // (1/8) * log2(e)

typedef __attribute__((ext_vector_type(8))) short short8;
typedef __attribute__((ext_vector_type(4))) short short4v;
typedef __attribute__((ext_vector_type(4))) float f32x4;

#define MFMA_BF16(A, B, C) __builtin_amdgcn_mfma_f32_16x16x32_bf16((A), (B), (C), 0, 0, 0)

static __device__ __forceinline__ short8 load8(const __hip_bfloat16* p) {
    return *(const short8*)p;
}

static __device__ __forceinline__ void async16(const void* g, void* l) {
    __builtin_amdgcn_global_load_lds(
        (const __attribute__((address_space(1))) unsigned int*)g,
        (__attribute__((address_space(3))) unsigned int*)l,
        16, 0, 0);
}

// ---------------------------------------------------------------------------
// Kernel 0: dtype detector (confirmed fp32 in round 2; keep for robustness)
// ---------------------------------------------------------------------------
__global__ void detect_kernel(const unsigned short* __restrict__ w, int* flag) {
    int cnt = 0;
    for (int i = threadIdx.x; i < 512; i += 64) {
        const unsigned e = (w[i] >> 7) & 0xFF;
        if (e >= 125) cnt++;
    }
#pragma unroll
    for (int o = 32; o; o >>= 1) cnt += __shfl_down(cnt, o);
    if (threadIdx.x == 0) *flag = (cnt > 8) ? 1 : 0;
}

// ---------------------------------------------------------------------------
// Kernel 0b: canonicalize inputs to bf16: [X | Wqkv | bqkv | Wout | bout]
// ---------------------------------------------------------------------------
__global__ __launch_bounds__(256) void canon_kernel(
    const void* __restrict__ s0, const void* __restrict__ s1,
    const void* __restrict__ s2, const void* __restrict__ s3,
    const void* __restrict__ s4,
    __hip_bfloat16* __restrict__ dst, const int* __restrict__ flag)
{
    const int idx = blockIdx.x * 256 + threadIdx.x;
    if (idx >= N_CANON) return;
    const void* src;
    int off;
    if (idx < N_X)                         { src = s0; off = idx; }
    else if (idx < N_X + N_WQ)             { src = s1; off = idx - N_X; }
    else if (idx < N_X + N_WQ + N_BQ)      { src = s2; off = idx - (N_X + N_WQ); }
    else if (idx < N_X + N_WQ + N_BQ + N_WO){ src = s3; off = idx - (N_X + N_WQ + N_BQ); }
    else                                   { src = s4; off = idx - (N_X + N_WQ + N_BQ + N_WO); }
    const bool isf32 = (*flag != 0);
    const float v = isf32 ? ((const float*)src)[off]
                          : __bfloat162float(((const __hip_bfloat16*)src)[off]);
    dst[idx] = __float2bfloat16(v);
}

// ---------------------------------------------------------------------------
// Kernel 1: QKV GEMM, m97 structure (128x128 tile, global_load_lds w=16).
// ---------------------------------------------------------------------------
__global__ __launch_bounds__(256) void qkv_gemm_kernel(
    const __hip_bfloat16* __restrict__ X,
    const __hip_bfloat16* __restrict__ W,
    const __hip_bfloat16* __restrict__ bias,
    __hip_bfloat16* __restrict__ Qs,
    __hip_bfloat16* __restrict__ Kb,
    __hip_bfloat16* __restrict__ Vt)
{
    constexpr int Kd = DMODEL;
    __shared__ __align__(16) __hip_bfloat16 As[128 * 32];
    __shared__ __align__(16) __hip_bfloat16 Bs[128 * 32];

    const int tid   = threadIdx.x;
    const int lane  = tid & 63;
    const int w     = tid >> 6;
    const int mTile = blockIdx.y * 128;
    const int nTile = blockIdx.x * 128;
    const int wm    = (w >> 1) * 64;
    const int wn    = (w & 1) * 64;
    const int lm    = lane & 15;
    const int lk    = (lane >> 4) * 8;

    f32x4 acc[4][4];
#pragma unroll
    for (int i = 0; i < 4; ++i)
#pragma unroll
        for (int j = 0; j < 4; ++j)
            acc[i][j] = (f32x4){0.f, 0.f, 0.f, 0.f};

    const int r0c = tid >> 2, p0c = tid & 3;
    const int r1c = (tid + 256) >> 2, p1c = tid & 3;

    for (int k0 = 0; k0 < Kd; k0 += 32) {
        __syncthreads();
        async16(&X[(size_t)(mTile + r0c) * Kd + k0 + p0c * 8], (char*)As + tid * 16);
        async16(&X[(size_t)(mTile + r1c) * Kd + k0 + p1c * 8], (char*)As + tid * 16 + 4096);
        async16(&W[(size_t)(nTile + r0c) * Kd + k0 + p0c * 8], (char*)Bs + tid * 16);
        async16(&W[(size_t)(nTile + r1c) * Kd + k0 + p1c * 8], (char*)Bs + tid * 16 + 4096);
        __syncthreads();

        short8 a[4], b[4];
#pragma unroll
        for (int i = 0; i < 4; ++i)
            a[i] = *(const short8*)&As[(wm + i * 16 + lm) * 32 + lk];
#pragma unroll
        for (int j = 0; j < 4; ++j)
            b[j] = *(const short8*)&Bs[(wn + j * 16 + lm) * 32 + lk];
#pragma unroll
        for (int i = 0; i < 4; ++i)
#pragma unroll
            for (int j = 0; j < 4; ++j)
                acc[i][j] = MFMA_BF16(a[i], b[j], acc[i][j]);
    }

    const int r0 = (lane >> 4) * 4;
#pragma unroll
    for (int j = 0; j < 4; ++j) {
        const int n  = nTile + wn + j * 16 + lm;
        const float bv = __bfloat162float(bias[n]);
        const int c = n >> 10;
        const int h = (n >> 6) & 15;
        const int d = n & 63;
#pragma unroll
        for (int i = 0; i < 4; ++i) {
#pragma unroll
            for (int r = 0; r < 4; ++r) {
                const int m  = mTile + wm + i * 16 + r0 + r;
                const int bb = m >> 11;
                const int s  = m & (SEQ - 1);
                const int bh = bb * NHEAD + h;
                const float v = acc[i][j][r] + bv;
                if (c == 0) {
                    Qs[(size_t)(bh * SEQ + s) * HDIM + d] = __float2bfloat16(v * QSCALE);
                } else if (c == 1) {
                    Kb[(size_t)(bh * SEQ + s) * HDIM + d] = __float2bfloat16(v);
                } else {
                    Vt[(size_t)(bh * HDIM + d) * SEQ + s] = __float2bfloat16(v);
                }
            }
        }
    }
}

// ---------------------------------------------------------------------------
// Kernel 2: cooperative causal flash attention, SPLIT-K pair-balanced.
//
// Round-11 change vs round 10 (63 us, MfmaUtil 11%, Occ 21%, VALUBusy 40%):
// only 2 waves/SIMD, both from the SAME barrier-locked WG -> softmax chain
// latency (~10 serial shfl/exp2 ops) barely hidden; 4.4K cy per chunk-slot
// vs ~650 cy of issue work.
//  - SPLIT-K: each pair (heavy qb=15-p, light qb=p) is split across 2 WGs
//    by key-range half: WG (p,kh) does chunks [kh*(qb+1),(kh+1)*(qb+1)) of
//    each block -> EVERY WG does exactly 17 chunks (deterministic balance,
//    any CU pairing is fine).  512 WGs x 8 waves = 2 WGs/CU = 4 waves/SIMD,
//    co-resident WGs uncorrelated -> barrier stalls overlap compute.
//    Partial (O f32, m, l) per half; tiny merge kernel combines.
//  - defer-max (T13, THR=8 in log2 units): skip alpha-rescale (exp2 +
//    4 serial shfl + 16 mul on the critical chain) when max didn't grow.
// ---------------------------------------------------------------------------
#define P_PITCH 72
__global__ __launch_bounds__(512, 4) void attn_kernel(
    const __hip_bfloat16* __restrict__ Qs,  // [B,H,S,Hd], pre-scaled
    const __hip_bfloat16* __restrict__ Kb,  // [B,H,S,Hd]
    const __hip_bfloat16* __restrict__ Vt,  // [B,H,Hd,S]
    float* __restrict__ Opart,              // [512 wg][2 ph][128][64] f32
    float* __restrict__ MLpart)             // [512 wg][2 ph][128][2] f32
{
    __shared__ __align__(16) __hip_bfloat16 Kt[2][64 * 64];
    __shared__ __align__(16) __hip_bfloat16 Vs[2][64 * 64];
    __shared__ __align__(16) __hip_bfloat16 Pall[8][16 * P_PITCH];

    const int tid  = threadIdx.x;
    const int lane = tid & 63;
    const int wv   = tid >> 6;              // 0..7
    const int p    = blockIdx.x >> 1;       // pair index 0..7
    const int kh   = blockIdx.x & 1;        // key-range half 0/1
    const int bh   = blockIdx.y;
    const int wgid = bh * 16 + blockIdx.x;

    const int lm  = lane & 15;
    const int q4  = lane >> 4;
    const int lk  = q4 * 8;
    const int swz = (lm & 3) << 4;

    __hip_bfloat16* P = Pall[wv];

    const __hip_bfloat16* Qbh = Qs + (size_t)bh * SEQ * HDIM;
    const __hip_bfloat16* Kbh = Kb + (size_t)bh * SEQ * HDIM;
    const __hip_bfloat16* Vbh = Vt + (size_t)bh * HDIM * SEQ;

    // staging address components: 512 threads, 8 threads x 16B per 128B row
    const int srow = tid >> 3;              // 0..63 (k-row for Kt, d-row for Vs)
    const int scb  = (tid & 7) ^ (srow & 7);   // XOR-swizzled column block

    for (int ph = 0; ph < 2; ++ph) {
        const int qb    = ph ? p : 15 - p;     // heavy first, then light
        const int wbase = qb * 128 + wv * 16;  // this wave's 16 q-rows
        const int nCh   = qb + 1;              // chunks this WG handles
        const int c0    = kh * nCh;            // first global chunk index

        short8 qa[2];
#pragma unroll
        for (int h = 0; h < 2; ++h)
            qa[h] = load8(&Qbh[(size_t)(wbase + lm) * HDIM + h * 32 + lk]);

        float m_run = NEG_SENT;
        float l_run = 0.f;
        f32x4 Oacc[4];
#pragma unroll
        for (int t = 0; t < 4; ++t) Oacc[t] = (f32x4){0.f, 0.f, 0.f, 0.f};

        int cur = 0;

        // prologue: prefetch first chunk into buffer 0
        async16(&Kbh[(size_t)(c0 * 64 + srow) * HDIM + scb * 8], (char*)Kt[0] + tid * 16);
        async16(&Vbh[(size_t)srow * SEQ + c0 * 64 + scb * 8],    (char*)Vs[0] + tid * 16);

        for (int ci = 0; ci < nCh; ++ci) {
            const int k0 = (c0 + ci) * 64;

            if (ci + 1 < nCh) {
                const int k1 = k0 + 64;
                async16(&Kbh[(size_t)(k1 + srow) * HDIM + scb * 8],
                        (char*)Kt[cur ^ 1] + tid * 16);
                async16(&Vbh[(size_t)srow * SEQ + k1 + scb * 8],
                        (char*)Vs[cur ^ 1] + tid * 16);
                // 4 outstanding, keep the 2 newest (next chunk) in flight
                asm volatile("s_waitcnt vmcnt(2)" ::: "memory");
            } else {
                asm volatile("s_waitcnt vmcnt(0)" ::: "memory");
            }
            __builtin_amdgcn_s_barrier();          // chunk tiles visible
            __builtin_amdgcn_sched_barrier(0);     // don't hoist ds_reads above

            if (k0 <= wbase + 15) {   // not fully masked for this wave
                const __hip_bfloat16* Kc = Kt[cur];
                const __hip_bfloat16* Vc = Vs[cur];

                short8 ka[4][2];
#pragma unroll
                for (int t = 0; t < 4; ++t)
#pragma unroll
                    for (int h = 0; h < 2; ++h)
                        ka[t][h] = *(const short8*)&Kc[(t * 16 + lm) * 64 +
                                                       (((h * 4 + q4) ^ (lm & 7)) * 8)];

                f32x4 sc[4];
#pragma unroll
                for (int t = 0; t < 4; ++t) sc[t] = (f32x4){0.f, 0.f, 0.f, 0.f};
#pragma unroll
                for (int t = 0; t < 4; ++t) {
                    sc[t] = MFMA_BF16(ka[t][0], qa[0], sc[t]);
                    sc[t] = MFMA_BF16(ka[t][1], qa[1], sc[t]);
                }

                if (k0 + 63 > wbase) {
                    const int row = wbase + lm;
#pragma unroll
                    for (int t = 0; t < 4; ++t)
#pragma unroll
                        for (int r = 0; r < 4; ++r) {
                            const int key = k0 + t * 16 + q4 * 4 + r;
                            if (key > row) sc[t][r] = NEG_SENT;
                        }
                }

                // online softmax (scores for q-row lm live in this lane)
                float mx = sc[0][0];
#pragma unroll
                for (int t = 0; t < 4; ++t)
#pragma unroll
                    for (int r = 0; r < 4; ++r) mx = fmaxf(mx, sc[t][r]);
                mx = fmaxf(mx, __shfl_xor(mx, 16));
                mx = fmaxf(mx, __shfl_xor(mx, 32));

                // defer-max (T13): only rescale when max grew by > 8 (log2)
                if (!__all(mx <= m_run + 8.0f)) {
                    const float mn = fmaxf(m_run, mx);
                    const float alpha = exp2f(m_run - mn);
                    m_run = mn;
                    l_run *= alpha;
#pragma unroll
                    for (int r = 0; r < 4; ++r) {
                        const float av = __shfl(alpha, q4 * 4 + r);
#pragma unroll
                        for (int t = 0; t < 4; ++t) Oacc[t][r] *= av;
                    }
                }

                float s = 0.f;
#pragma unroll
                for (int t = 0; t < 4; ++t)
#pragma unroll
                    for (int r = 0; r < 4; ++r) {
                        const float pv = exp2f(sc[t][r] - m_run);
                        sc[t][r] = pv;
                        s += pv;
                    }
                s += __shfl_xor(s, 16);
                s += __shfl_xor(s, 32);
                l_run += s;

#pragma unroll
                for (int t = 0; t < 4; ++t) {
                    short4v pk;
#pragma unroll
                    for (int r = 0; r < 4; ++r)
                        pk[r] = (short)__bfloat16_as_ushort(__float2bfloat16(sc[t][r]));
                    const int col = (t * 16 + q4 * 4) ^ swz;
                    *(short4v*)&P[lm * P_PITCH + col] = pk;
                }

#pragma unroll
                for (int h = 0; h < 2; ++h) {
                    const short8 pa = *(const short8*)&P[lm * P_PITCH + ((h * 32 + lk) ^ swz)];
#pragma unroll
                    for (int t = 0; t < 4; ++t) {
                        const short8 vb = *(const short8*)&Vc[(t * 16 + lm) * 64 +
                                                              (((h * 4 + q4) ^ (lm & 7)) * 8)];
                        Oacc[t] = MFMA_BF16(pa, vb, Oacc[t]);
                    }
                }
            }

            __builtin_amdgcn_s_barrier();   // all waves done reading buf[cur]
            cur ^= 1;
        }

        // --- epilogue: store f32 partials for this phase's 16 rows/wave ---
        const size_t pbase = ((size_t)wgid * 2 + ph) * 128;
#pragma unroll
        for (int t = 0; t < 4; ++t)
#pragma unroll
            for (int r = 0; r < 4; ++r)
                Opart[(pbase + wv * 16 + q4 * 4 + r) * 64 + t * 16 + lm] = Oacc[t][r];
        if (lane < 16) {
            MLpart[(pbase + wv * 16 + lane) * 2 + 0] = m_run;
            MLpart[(pbase + wv * 16 + lane) * 2 + 1] = l_run;
        }
    }
}

// ---------------------------------------------------------------------------
// Kernel 2b: merge the two key-half partials per row, normalize, write bf16.
// One thread per (row, 16-d group): 32bh * 2048s * 4 = 262144 threads.
// ---------------------------------------------------------------------------
__global__ __launch_bounds__(256) void attn_merge_kernel(
    const float* __restrict__ Opart, const float* __restrict__ MLpart,
    __hip_bfloat16* __restrict__ O)
{
    const int idx  = blockIdx.x * 256 + threadIdx.x;
    const int d16  = idx & 3;
    const int grow = idx >> 2;             // bh*2048 + s
    const int bh   = grow >> 11;
    const int s    = grow & 2047;
    const int qb   = s >> 7;
    const int rin  = s & 127;
    const int p    = (qb >= 8) ? (15 - qb) : qb;
    const int ph   = (qb >= 8) ? 0 : 1;
    const size_t r0 = ((size_t)(bh * 16 + p * 2 + 0) * 2 + ph) * 128 + rin;
    const size_t r1 = ((size_t)(bh * 16 + p * 2 + 1) * 2 + ph) * 128 + rin;

    const float m1 = MLpart[r0 * 2], l1 = MLpart[r0 * 2 + 1];
    const float m2 = MLpart[r1 * 2], l2 = MLpart[r1 * 2 + 1];
    const float mm = fmaxf(m1, m2);
    const float a1 = exp2f(m1 - mm), a2 = exp2f(m2 - mm);
    const float inv = 1.0f / (a1 * l1 + a2 * l2);

    const f32x4* O1 = (const f32x4*)&Opart[r0 * 64 + d16 * 16];
    const f32x4* O2 = (const f32x4*)&Opart[r1 * 64 + d16 * 16];

    short8 out[2];
#pragma unroll
    for (int v = 0; v < 4; ++v) {
        const f32x4 x1 = O1[v], x2 = O2[v];
#pragma unroll
        for (int j = 0; j < 4; ++j)
            out[v >> 1][(v & 1) * 4 + j] = (short)__bfloat16_as_ushort(
                __float2bfloat16((a1 * x1[j] + a2 * x2[j]) * inv));
    }
    const int b = bh >> 4, hh = bh & 15;
    __hip_bfloat16* dst = &O[((size_t)b * SEQ + s) * DMODEL + hh * 64 + d16 * 16];
    ((short8*)dst)[0] = out[0];
    ((short8*)dst)[1] = out[1];
}

// ---------------------------------------------------------------------------
// Kernel 3: out projection, m97 structure.
// ---------------------------------------------------------------------------
__global__ __launch_bounds__(256) void proj_gemm_kernel(
    const __hip_bfloat16* __restrict__ A,
    const __hip_bfloat16* __restrict__ W,
    const __hip_bfloat16* __restrict__ bias,
    void* __restrict__ outv,
    const int* __restrict__ flag)
{
    constexpr int Kd = DMODEL;
    __shared__ __align__(16) __hip_bfloat16 As[128 * 32];
    __shared__ __align__(16) __hip_bfloat16 Bs[128 * 32];

    const int tid   = threadIdx.x;
    const int lane  = tid & 63;
    const int w     = tid >> 6;
    const int mTile = blockIdx.y * 128;
    const int nTile = blockIdx.x * 128;
    const int wm    = (w >> 1) * 64;
    const int wn    = (w & 1) * 64;
    const int lm    = lane & 15;
    const int lk    = (lane >> 4) * 8;
    const bool f32out = (*flag != 0);

    f32x4 acc[4][4];
#pragma unroll
    for (int i = 0; i < 4; ++i)
#pragma unroll
        for (int j = 0; j < 4; ++j)
            acc[i][j] = (f32x4){0.f, 0.f, 0.f, 0.f};

    const int r0c = tid >> 2, p0c = tid & 3;
    const int r1c = (tid + 256) >> 2, p1c = tid & 3;

    for (int k0 = 0; k0 < Kd; k0 += 32) {
        __syncthreads();
        async16(&A[(size_t)(mTile + r0c) * Kd + k0 + p0c * 8], (char*)As + tid * 16);
        async16(&A[(size_t)(mTile + r1c) * Kd + k0 + p1c * 8], (char*)As + tid * 16 + 4096);
        async16(&W[(size_t)(nTile + r0c) * Kd + k0 + p0c * 8], (char*)Bs + tid * 16);
        async16(&W[(size_t)(nTile + r1c) * Kd + k0 + p1c * 8], (char*)Bs + tid * 16 + 4096);
        __syncthreads();

        short8 a[4], b[4];
#pragma unroll
        for (int i = 0; i < 4; ++i)
            a[i] = *(const short8*)&As[(wm + i * 16 + lm) * 32 + lk];
#pragma unroll
        for (int j = 0; j < 4; ++j)
            b[j] = *(const short8*)&Bs[(wn + j * 16 + lm) * 32 + lk];
#pragma unroll
        for (int i = 0; i < 4; ++i)
#pragma unroll
            for (int j = 0; j < 4; ++j)
                acc[i][j] = MFMA_BF16(a[i], b[j], acc[i][j]);
    }

    const int r0 = (lane >> 4) * 4;
#pragma unroll
    for (int j = 0; j < 4; ++j) {
        const int n = nTile + wn + j * 16 + lm;
        const float bv = __bfloat162float(bias[n]);
#pragma unroll
        for (int i = 0; i < 4; ++i) {
#pragma unroll
            for (int r = 0; r < 4; ++r) {
                const size_t m = mTile + wm + i * 16 + r0 + r;
                const float v = acc[i][j][r] + bv;
                if (f32out) ((float*)outv)[m * DMODEL + n] = v;
                else ((__hip_bfloat16*)outv)[m * DMODEL + n] = __float2bfloat16(v);
            }
        }
    }
}

// ---------------------------------------------------------------------------
extern "C" void kernel_launch(void* const* d_in, const int* in_sizes, int n_in,
                              void* d_out, int out_size, void* d_ws, size_t ws_size,
                              hipStream_t stream) {
    // Workspace layout (bytes):
    // [flag:256][canon bf16][Qs][Kb][Vt][Ao][Opart f32][MLpart f32]
    const size_t OFF_CANON = 256;
    const size_t OFF_QS = OFF_CANON + (size_t)N_CANON * 2;
    const size_t OFF_KB = OFF_QS + (size_t)NTOK * DMODEL * 2;
    const size_t OFF_VT = OFF_KB + (size_t)NTOK * DMODEL * 2;
    const size_t OFF_AO = OFF_VT + (size_t)NTOK * DMODEL * 2;
    const size_t OFF_OP = OFF_AO + (size_t)NTOK * DMODEL * 2;
    const size_t OFF_ML = OFF_OP + (size_t)512 * 2 * 128 * 64 * 4;   // 33.55 MB

    char* wsb = (char*)d_ws;
    int* flag = (int*)wsb;
    __hip_bfloat16* canon = (__hip_bfloat16*)(wsb + OFF_CANON);
    __hip_bfloat16* Xc = canon;
    __hip_bfloat16* Wq = Xc + N_X;
    __hip_bfloat16* Bq = Wq + N_WQ;
    __hip_bfloat16* Wo = Bq + N_BQ;
    __hip_bfloat16* Bo = Wo + N_WO;
    __hip_bfloat16* Qs = (__hip_bfloat16*)(wsb + OFF_QS);
    __hip_bfloat16* Kb = (__hip_bfloat16*)(wsb + OFF_KB);
    __hip_bfloat16* Vt = (__hip_bfloat16*)(wsb + OFF_VT);
    __hip_bfloat16* Ao = (__hip_bfloat16*)(wsb + OFF_AO);
    float* Opart = (float*)(wsb + OFF_OP);
    float* MLpart = (float*)(wsb + OFF_ML);

    // 0) dtype detect + canonicalize
    detect_kernel<<<1, 64, 0, stream>>>((const unsigned short*)d_in[1], flag);
    canon_kernel<<<(N_CANON + 255) / 256, 256, 0, stream>>>(
        d_in[0], d_in[1], d_in[2], d_in[3], d_in[4], canon, flag);

    // 1) QKV GEMM
    {
        dim3 grid(3 * DMODEL / 128, NTOK / 128);
        qkv_gemm_kernel<<<grid, 256, 0, stream>>>(Xc, Wq, Bq, Qs, Kb, Vt);
    }
    // 2) Attention: split-K pair-balanced, grid (16, B*H) = 512 WGs of 8
    //    waves; every WG exactly 17 chunks; 2 WGs/CU -> 4 waves/SIMD.
    {
        dim3 grid(16, BATCH * NHEAD);
        attn_kernel<<<grid, 512, 0, stream>>>(Qs, Kb, Vt, Opart, MLpart);
        attn_merge_kernel<<<(NTOK * NHEAD * 4) / 256, 256, 0, stream>>>(
            Opart, MLpart, Ao);
    }
    // 3) Out projection
    {
        dim3 grid(DMODEL / 128, NTOK / 128);
        proj_gemm_kernel<<<grid, 256, 0, stream>>>(Ao, Wo, Bo, d_out, flag);
    }
}

// Round 3
// 205.970 us; speedup vs baseline: 1.1284x; 1.0335x over previous
//
#include <hip/hip_runtime.h>
#include <hip/hip_bf16.h>

// Sizes (fixed): B=2, S=2048, D=1024, H=16, Hd=64
#define SEQ    2048
#define DMODEL 1024
#define NHEAD  16
#define HDIM   64
#define BATCH  2
#define NTOK   (BATCH * SEQ)           // 4096

#define N_X   (NTOK * DMODEL)
#define N_WQ  (3 * DMODEL * DMODEL)
#define N_BQ  (3 * DMODEL)
#define N_WO  (DMODEL * DMODEL)
#define N_BO  (DMODEL)
#define N_CANON (N_X + N_WQ + N_BQ + N_WO + N_BO)   // 8,392,704

#define NEG_SENT (-1.0e30f)
#define QSCALE 0.1803368801111f        // (1/8) * log2(e)

typedef __attribute__((ext_vector_type(8))) short short8;
typedef __attribute__((ext_vector_type(4))) short short4v;
typedef __attribute__((ext_vector_type(4))) float f32x4;

#define MFMA_BF16(A, B, C) __builtin_amdgcn_mfma_f32_16x16x32_bf16((A), (B), (C), 0, 0, 0)

static __device__ __forceinline__ short8 load8(const __hip_bfloat16* p) {
    return *(const short8*)p;
}

static __device__ __forceinline__ void async16(const void* g, void* l) {
    __builtin_amdgcn_global_load_lds(
        (const __attribute__((address_space(1))) unsigned int*)g,
        (__attribute__((address_space(3))) unsigned int*)l,
        16, 0, 0);
}

// ---------------------------------------------------------------------------
// Kernel 0: dtype detector (confirmed fp32 in round 2; keep for robustness)
// ---------------------------------------------------------------------------
__global__ void detect_kernel(const unsigned short* __restrict__ w, int* flag) {
    int cnt = 0;
    for (int i = threadIdx.x; i < 512; i += 64) {
        const unsigned e = (w[i] >> 7) & 0xFF;
        if (e >= 125) cnt++;
    }
#pragma unroll
    for (int o = 32; o; o >>= 1) cnt += __shfl_down(cnt, o);
    if (threadIdx.x == 0) *flag = (cnt > 8) ? 1 : 0;
}

// ---------------------------------------------------------------------------
// Kernel 0b: canonicalize inputs to bf16: [X | Wqkv | bqkv | Wout | bout]
// ---------------------------------------------------------------------------
__global__ __launch_bounds__(256) void canon_kernel(
    const void* __restrict__ s0, const void* __restrict__ s1,
    const void* __restrict__ s2, const void* __restrict__ s3,
    const void* __restrict__ s4,
    __hip_bfloat16* __restrict__ dst, const int* __restrict__ flag)
{
    const int idx = blockIdx.x * 256 + threadIdx.x;
    if (idx >= N_CANON) return;
    const void* src;
    int off;
    if (idx < N_X)                         { src = s0; off = idx; }
    else if (idx < N_X + N_WQ)             { src = s1; off = idx - N_X; }
    else if (idx < N_X + N_WQ + N_BQ)      { src = s2; off = idx - (N_X + N_WQ); }
    else if (idx < N_X + N_WQ + N_BQ + N_WO){ src = s3; off = idx - (N_X + N_WQ + N_BQ); }
    else                                   { src = s4; off = idx - (N_X + N_WQ + N_BQ + N_WO); }
    const bool isf32 = (*flag != 0);
    const float v = isf32 ? ((const float*)src)[off]
                          : __bfloat162float(((const __hip_bfloat16*)src)[off]);
    dst[idx] = __float2bfloat16(v);
}

// ---------------------------------------------------------------------------
// Kernel 1: QKV GEMM, m97 structure + DOUBLE-BUFFERED staging (counted vmcnt).
// Round-12 change: the per-K-step vmcnt(0) drain (~300-500 cy x 32 iters)
// was the dominant cost (MfmaUtil 14.5%, all pipes idle).  Now stage k+1
// into buf^1 before computing k; s_waitcnt vmcnt(4) keeps the 4 newest
// loads in flight (never drains mid-loop, T4).  V epilogue: packed 8B
// stores (4 consecutive s per thread) instead of scalar 2B scatter.
// ---------------------------------------------------------------------------
__global__ __launch_bounds__(256) void qkv_gemm_kernel(
    const __hip_bfloat16* __restrict__ X,
    const __hip_bfloat16* __restrict__ W,
    const __hip_bfloat16* __restrict__ bias,
    __hip_bfloat16* __restrict__ Qs,
    __hip_bfloat16* __restrict__ Kb,
    __hip_bfloat16* __restrict__ Vt)
{
    constexpr int Kd = DMODEL;
    __shared__ __align__(16) __hip_bfloat16 As[2][128 * 32];
    __shared__ __align__(16) __hip_bfloat16 Bs[2][128 * 32];

    const int tid   = threadIdx.x;
    const int lane  = tid & 63;
    const int w     = tid >> 6;
    const int mTile = blockIdx.y * 128;
    const int nTile = blockIdx.x * 128;
    const int wm    = (w >> 1) * 64;
    const int wn    = (w & 1) * 64;
    const int lm    = lane & 15;
    const int lk    = (lane >> 4) * 8;

    f32x4 acc[4][4];
#pragma unroll
    for (int i = 0; i < 4; ++i)
#pragma unroll
        for (int j = 0; j < 4; ++j)
            acc[i][j] = (f32x4){0.f, 0.f, 0.f, 0.f};

    const int r0c = tid >> 2, p0c = tid & 3;
    const int r1c = (tid + 256) >> 2;

    const __hip_bfloat16* gA0 = &X[(size_t)(mTile + r0c) * Kd + p0c * 8];
    const __hip_bfloat16* gA1 = &X[(size_t)(mTile + r1c) * Kd + p0c * 8];
    const __hip_bfloat16* gB0 = &W[(size_t)(nTile + r0c) * Kd + p0c * 8];
    const __hip_bfloat16* gB1 = &W[(size_t)(nTile + r1c) * Kd + p0c * 8];

    // prologue: stage k0=0 into buffer 0
    async16(gA0, (char*)As[0] + tid * 16);
    async16(gA1, (char*)As[0] + tid * 16 + 4096);
    async16(gB0, (char*)Bs[0] + tid * 16);
    async16(gB1, (char*)Bs[0] + tid * 16 + 4096);

    int cur = 0;
    constexpr int NIT = Kd / 32;
    for (int it = 0; it < NIT; ++it) {
        if (it + 1 < NIT) {
            const int k1 = (it + 1) * 32;
            async16(gA0 + k1, (char*)As[cur ^ 1] + tid * 16);
            async16(gA1 + k1, (char*)As[cur ^ 1] + tid * 16 + 4096);
            async16(gB0 + k1, (char*)Bs[cur ^ 1] + tid * 16);
            async16(gB1 + k1, (char*)Bs[cur ^ 1] + tid * 16 + 4096);
            asm volatile("s_waitcnt vmcnt(4)" ::: "memory");
        } else {
            asm volatile("s_waitcnt vmcnt(0)" ::: "memory");
        }
        __builtin_amdgcn_s_barrier();          // buf[cur] visible to all waves
        __builtin_amdgcn_sched_barrier(0);

        const __hip_bfloat16* Ac = As[cur];
        const __hip_bfloat16* Bc = Bs[cur];
        short8 a[4], b[4];
#pragma unroll
        for (int i = 0; i < 4; ++i)
            a[i] = *(const short8*)&Ac[(wm + i * 16 + lm) * 32 + lk];
#pragma unroll
        for (int j = 0; j < 4; ++j)
            b[j] = *(const short8*)&Bc[(wn + j * 16 + lm) * 32 + lk];
#pragma unroll
        for (int i = 0; i < 4; ++i)
#pragma unroll
            for (int j = 0; j < 4; ++j)
                acc[i][j] = MFMA_BF16(a[i], b[j], acc[i][j]);

        __builtin_amdgcn_s_barrier();          // all waves done reading buf[cur]
        cur ^= 1;
    }

    const int r0 = (lane >> 4) * 4;
#pragma unroll
    for (int j = 0; j < 4; ++j) {
        const int n  = nTile + wn + j * 16 + lm;
        const float bv = __bfloat162float(bias[n]);
        const int c = n >> 10;
        const int h = (n >> 6) & 15;
        const int d = n & 63;
#pragma unroll
        for (int i = 0; i < 4; ++i) {
            if (c == 2) {
                // V: 4 consecutive s per thread -> one packed 8B store
                const int m0 = mTile + wm + i * 16 + r0;
                const int bb = m0 >> 11;
                const int s0 = m0 & (SEQ - 1);
                const int bh = bb * NHEAD + h;
                short4v pk;
#pragma unroll
                for (int r = 0; r < 4; ++r)
                    pk[r] = (short)__bfloat16_as_ushort(
                        __float2bfloat16(acc[i][j][r] + bv));
                *(short4v*)&Vt[(size_t)(bh * HDIM + d) * SEQ + s0] = pk;
            } else {
#pragma unroll
                for (int r = 0; r < 4; ++r) {
                    const int m  = mTile + wm + i * 16 + r0 + r;
                    const int bb = m >> 11;
                    const int s  = m & (SEQ - 1);
                    const int bh = bb * NHEAD + h;
                    const float v = acc[i][j][r] + bv;
                    if (c == 0) {
                        Qs[(size_t)(bh * SEQ + s) * HDIM + d] = __float2bfloat16(v * QSCALE);
                    } else {
                        Kb[(size_t)(bh * SEQ + s) * HDIM + d] = __float2bfloat16(v);
                    }
                }
            }
        }
    }
}

// ---------------------------------------------------------------------------
// Kernel 2: cooperative causal flash attention, SPLIT-K pair-balanced.
// (unchanged from round 11)
// ---------------------------------------------------------------------------
#define P_PITCH 72
__global__ __launch_bounds__(512, 4) void attn_kernel(
    const __hip_bfloat16* __restrict__ Qs,  // [B,H,S,Hd], pre-scaled
    const __hip_bfloat16* __restrict__ Kb,  // [B,H,S,Hd]
    const __hip_bfloat16* __restrict__ Vt,  // [B,H,Hd,S]
    float* __restrict__ Opart,              // [512 wg][2 ph][128][64] f32
    float* __restrict__ MLpart)             // [512 wg][2 ph][128][2] f32
{
    __shared__ __align__(16) __hip_bfloat16 Kt[2][64 * 64];
    __shared__ __align__(16) __hip_bfloat16 Vs[2][64 * 64];
    __shared__ __align__(16) __hip_bfloat16 Pall[8][16 * P_PITCH];

    const int tid  = threadIdx.x;
    const int lane = tid & 63;
    const int wv   = tid >> 6;              // 0..7
    const int p    = blockIdx.x >> 1;       // pair index 0..7
    const int kh   = blockIdx.x & 1;        // key-range half 0/1
    const int bh   = blockIdx.y;
    const int wgid = bh * 16 + blockIdx.x;

    const int lm  = lane & 15;
    const int q4  = lane >> 4;
    const int lk  = q4 * 8;
    const int swz = (lm & 3) << 4;

    __hip_bfloat16* P = Pall[wv];

    const __hip_bfloat16* Qbh = Qs + (size_t)bh * SEQ * HDIM;
    const __hip_bfloat16* Kbh = Kb + (size_t)bh * SEQ * HDIM;
    const __hip_bfloat16* Vbh = Vt + (size_t)bh * HDIM * SEQ;

    // staging address components: 512 threads, 8 threads x 16B per 128B row
    const int srow = tid >> 3;              // 0..63 (k-row for Kt, d-row for Vs)
    const int scb  = (tid & 7) ^ (srow & 7);   // XOR-swizzled column block

    for (int ph = 0; ph < 2; ++ph) {
        const int qb    = ph ? p : 15 - p;     // heavy first, then light
        const int wbase = qb * 128 + wv * 16;  // this wave's 16 q-rows
        const int nCh   = qb + 1;              // chunks this WG handles
        const int c0    = kh * nCh;            // first global chunk index

        short8 qa[2];
#pragma unroll
        for (int h = 0; h < 2; ++h)
            qa[h] = load8(&Qbh[(size_t)(wbase + lm) * HDIM + h * 32 + lk]);

        float m_run = NEG_SENT;
        float l_run = 0.f;
        f32x4 Oacc[4];
#pragma unroll
        for (int t = 0; t < 4; ++t) Oacc[t] = (f32x4){0.f, 0.f, 0.f, 0.f};

        int cur = 0;

        // prologue: prefetch first chunk into buffer 0
        async16(&Kbh[(size_t)(c0 * 64 + srow) * HDIM + scb * 8], (char*)Kt[0] + tid * 16);
        async16(&Vbh[(size_t)srow * SEQ + c0 * 64 + scb * 8],    (char*)Vs[0] + tid * 16);

        for (int ci = 0; ci < nCh; ++ci) {
            const int k0 = (c0 + ci) * 64;

            if (ci + 1 < nCh) {
                const int k1 = k0 + 64;
                async16(&Kbh[(size_t)(k1 + srow) * HDIM + scb * 8],
                        (char*)Kt[cur ^ 1] + tid * 16);
                async16(&Vbh[(size_t)srow * SEQ + k1 + scb * 8],
                        (char*)Vs[cur ^ 1] + tid * 16);
                // 4 outstanding, keep the 2 newest (next chunk) in flight
                asm volatile("s_waitcnt vmcnt(2)" ::: "memory");
            } else {
                asm volatile("s_waitcnt vmcnt(0)" ::: "memory");
            }
            __builtin_amdgcn_s_barrier();          // chunk tiles visible
            __builtin_amdgcn_sched_barrier(0);     // don't hoist ds_reads above

            if (k0 <= wbase + 15) {   // not fully masked for this wave
                const __hip_bfloat16* Kc = Kt[cur];
                const __hip_bfloat16* Vc = Vs[cur];

                short8 ka[4][2];
#pragma unroll
                for (int t = 0; t < 4; ++t)
#pragma unroll
                    for (int h = 0; h < 2; ++h)
                        ka[t][h] = *(const short8*)&Kc[(t * 16 + lm) * 64 +
                                                       (((h * 4 + q4) ^ (lm & 7)) * 8)];

                f32x4 sc[4];
#pragma unroll
                for (int t = 0; t < 4; ++t) sc[t] = (f32x4){0.f, 0.f, 0.f, 0.f};
#pragma unroll
                for (int t = 0; t < 4; ++t) {
                    sc[t] = MFMA_BF16(ka[t][0], qa[0], sc[t]);
                    sc[t] = MFMA_BF16(ka[t][1], qa[1], sc[t]);
                }

                if (k0 + 63 > wbase) {
                    const int row = wbase + lm;
#pragma unroll
                    for (int t = 0; t < 4; ++t)
#pragma unroll
                        for (int r = 0; r < 4; ++r) {
                            const int key = k0 + t * 16 + q4 * 4 + r;
                            if (key > row) sc[t][r] = NEG_SENT;
                        }
                }

                // online softmax (scores for q-row lm live in this lane)
                float mx = sc[0][0];
#pragma unroll
                for (int t = 0; t < 4; ++t)
#pragma unroll
                    for (int r = 0; r < 4; ++r) mx = fmaxf(mx, sc[t][r]);
                mx = fmaxf(mx, __shfl_xor(mx, 16));
                mx = fmaxf(mx, __shfl_xor(mx, 32));

                // defer-max (T13): only rescale when max grew by > 8 (log2)
                if (!__all(mx <= m_run + 8.0f)) {
                    const float mn = fmaxf(m_run, mx);
                    const float alpha = exp2f(m_run - mn);
                    m_run = mn;
                    l_run *= alpha;
#pragma unroll
                    for (int r = 0; r < 4; ++r) {
                        const float av = __shfl(alpha, q4 * 4 + r);
#pragma unroll
                        for (int t = 0; t < 4; ++t) Oacc[t][r] *= av;
                    }
                }

                float s = 0.f;
#pragma unroll
                for (int t = 0; t < 4; ++t)
#pragma unroll
                    for (int r = 0; r < 4; ++r) {
                        const float pv = exp2f(sc[t][r] - m_run);
                        sc[t][r] = pv;
                        s += pv;
                    }
                s += __shfl_xor(s, 16);
                s += __shfl_xor(s, 32);
                l_run += s;

#pragma unroll
                for (int t = 0; t < 4; ++t) {
                    short4v pk;
#pragma unroll
                    for (int r = 0; r < 4; ++r)
                        pk[r] = (short)__bfloat16_as_ushort(__float2bfloat16(sc[t][r]));
                    const int col = (t * 16 + q4 * 4) ^ swz;
                    *(short4v*)&P[lm * P_PITCH + col] = pk;
                }

#pragma unroll
                for (int h = 0; h < 2; ++h) {
                    const short8 pa = *(const short8*)&P[lm * P_PITCH + ((h * 32 + lk) ^ swz)];
#pragma unroll
                    for (int t = 0; t < 4; ++t) {
                        const short8 vb = *(const short8*)&Vc[(t * 16 + lm) * 64 +
                                                              (((h * 4 + q4) ^ (lm & 7)) * 8)];
                        Oacc[t] = MFMA_BF16(pa, vb, Oacc[t]);
                    }
                }
            }

            __builtin_amdgcn_s_barrier();   // all waves done reading buf[cur]
            cur ^= 1;
        }

        // --- epilogue: store f32 partials for this phase's 16 rows/wave ---
        const size_t pbase = ((size_t)wgid * 2 + ph) * 128;
#pragma unroll
        for (int t = 0; t < 4; ++t)
#pragma unroll
            for (int r = 0; r < 4; ++r)
                Opart[(pbase + wv * 16 + q4 * 4 + r) * 64 + t * 16 + lm] = Oacc[t][r];
        if (lane < 16) {
            MLpart[(pbase + wv * 16 + lane) * 2 + 0] = m_run;
            MLpart[(pbase + wv * 16 + lane) * 2 + 1] = l_run;
        }
    }
}

// ---------------------------------------------------------------------------
// Kernel 2b: merge the two key-half partials per row, normalize, write bf16.
// One thread per (row, 16-d group): 32bh * 2048s * 4 = 262144 threads.
// ---------------------------------------------------------------------------
__global__ __launch_bounds__(256) void attn_merge_kernel(
    const float* __restrict__ Opart, const float* __restrict__ MLpart,
    __hip_bfloat16* __restrict__ O)
{
    const int idx  = blockIdx.x * 256 + threadIdx.x;
    const int d16  = idx & 3;
    const int grow = idx >> 2;             // bh*2048 + s
    const int bh   = grow >> 11;
    const int s    = grow & 2047;
    const int qb   = s >> 7;
    const int rin  = s & 127;
    const int p    = (qb >= 8) ? (15 - qb) : qb;
    const int ph   = (qb >= 8) ? 0 : 1;
    const size_t r0 = ((size_t)(bh * 16 + p * 2 + 0) * 2 + ph) * 128 + rin;
    const size_t r1 = ((size_t)(bh * 16 + p * 2 + 1) * 2 + ph) * 128 + rin;

    const float m1 = MLpart[r0 * 2], l1 = MLpart[r0 * 2 + 1];
    const float m2 = MLpart[r1 * 2], l2 = MLpart[r1 * 2 + 1];
    const float mm = fmaxf(m1, m2);
    const float a1 = exp2f(m1 - mm), a2 = exp2f(m2 - mm);
    const float inv = 1.0f / (a1 * l1 + a2 * l2);

    const f32x4* O1 = (const f32x4*)&Opart[r0 * 64 + d16 * 16];
    const f32x4* O2 = (const f32x4*)&Opart[r1 * 64 + d16 * 16];

    short8 out[2];
#pragma unroll
    for (int v = 0; v < 4; ++v) {
        const f32x4 x1 = O1[v], x2 = O2[v];
#pragma unroll
        for (int j = 0; j < 4; ++j)
            out[v >> 1][(v & 1) * 4 + j] = (short)__bfloat16_as_ushort(
                __float2bfloat16((a1 * x1[j] + a2 * x2[j]) * inv));
    }
    const int b = bh >> 4, hh = bh & 15;
    __hip_bfloat16* dst = &O[((size_t)b * SEQ + s) * DMODEL + hh * 64 + d16 * 16];
    ((short8*)dst)[0] = out[0];
    ((short8*)dst)[1] = out[1];
}

// ---------------------------------------------------------------------------
// Kernel 3: out projection, m97 structure + DOUBLE-BUFFERED staging.
// ---------------------------------------------------------------------------
__global__ __launch_bounds__(256) void proj_gemm_kernel(
    const __hip_bfloat16* __restrict__ A,
    const __hip_bfloat16* __restrict__ W,
    const __hip_bfloat16* __restrict__ bias,
    void* __restrict__ outv,
    const int* __restrict__ flag)
{
    constexpr int Kd = DMODEL;
    __shared__ __align__(16) __hip_bfloat16 As[2][128 * 32];
    __shared__ __align__(16) __hip_bfloat16 Bs[2][128 * 32];

    const int tid   = threadIdx.x;
    const int lane  = tid & 63;
    const int w     = tid >> 6;
    const int mTile = blockIdx.y * 128;
    const int nTile = blockIdx.x * 128;
    const int wm    = (w >> 1) * 64;
    const int wn    = (w & 1) * 64;
    const int lm    = lane & 15;
    const int lk    = (lane >> 4) * 8;
    const bool f32out = (*flag != 0);

    f32x4 acc[4][4];
#pragma unroll
    for (int i = 0; i < 4; ++i)
#pragma unroll
        for (int j = 0; j < 4; ++j)
            acc[i][j] = (f32x4){0.f, 0.f, 0.f, 0.f};

    const int r0c = tid >> 2, p0c = tid & 3;
    const int r1c = (tid + 256) >> 2;

    const __hip_bfloat16* gA0 = &A[(size_t)(mTile + r0c) * Kd + p0c * 8];
    const __hip_bfloat16* gA1 = &A[(size_t)(mTile + r1c) * Kd + p0c * 8];
    const __hip_bfloat16* gB0 = &W[(size_t)(nTile + r0c) * Kd + p0c * 8];
    const __hip_bfloat16* gB1 = &W[(size_t)(nTile + r1c) * Kd + p0c * 8];

    async16(gA0, (char*)As[0] + tid * 16);
    async16(gA1, (char*)As[0] + tid * 16 + 4096);
    async16(gB0, (char*)Bs[0] + tid * 16);
    async16(gB1, (char*)Bs[0] + tid * 16 + 4096);

    int cur = 0;
    constexpr int NIT = Kd / 32;
    for (int it = 0; it < NIT; ++it) {
        if (it + 1 < NIT) {
            const int k1 = (it + 1) * 32;
            async16(gA0 + k1, (char*)As[cur ^ 1] + tid * 16);
            async16(gA1 + k1, (char*)As[cur ^ 1] + tid * 16 + 4096);
            async16(gB0 + k1, (char*)Bs[cur ^ 1] + tid * 16);
            async16(gB1 + k1, (char*)Bs[cur ^ 1] + tid * 16 + 4096);
            asm volatile("s_waitcnt vmcnt(4)" ::: "memory");
        } else {
            asm volatile("s_waitcnt vmcnt(0)" ::: "memory");
        }
        __builtin_amdgcn_s_barrier();
        __builtin_amdgcn_sched_barrier(0);

        const __hip_bfloat16* Ac = As[cur];
        const __hip_bfloat16* Bc = Bs[cur];
        short8 a[4], b[4];
#pragma unroll
        for (int i = 0; i < 4; ++i)
            a[i] = *(const short8*)&Ac[(wm + i * 16 + lm) * 32 + lk];
#pragma unroll
        for (int j = 0; j < 4; ++j)
            b[j] = *(const short8*)&Bc[(wn + j * 16 + lm) * 32 + lk];
#pragma unroll
        for (int i = 0; i < 4; ++i)
#pragma unroll
            for (int j = 0; j < 4; ++j)
                acc[i][j] = MFMA_BF16(a[i], b[j], acc[i][j]);

        __builtin_amdgcn_s_barrier();
        cur ^= 1;
    }

    const int r0 = (lane >> 4) * 4;
#pragma unroll
    for (int j = 0; j < 4; ++j) {
        const int n = nTile + wn + j * 16 + lm;
        const float bv = __bfloat162float(bias[n]);
#pragma unroll
        for (int i = 0; i < 4; ++i) {
#pragma unroll
            for (int r = 0; r < 4; ++r) {
                const size_t m = mTile + wm + i * 16 + r0 + r;
                const float v = acc[i][j][r] + bv;
                if (f32out) ((float*)outv)[m * DMODEL + n] = v;
                else ((__hip_bfloat16*)outv)[m * DMODEL + n] = __float2bfloat16(v);
            }
        }
    }
}

// ---------------------------------------------------------------------------
extern "C" void kernel_launch(void* const* d_in, const int* in_sizes, int n_in,
                              void* d_out, int out_size, void* d_ws, size_t ws_size,
                              hipStream_t stream) {
    // Workspace layout (bytes):
    // [flag:256][canon bf16][Qs][Kb][Vt][Ao][Opart f32][MLpart f32]
    const size_t OFF_CANON = 256;
    const size_t OFF_QS = OFF_CANON + (size_t)N_CANON * 2;
    const size_t OFF_KB = OFF_QS + (size_t)NTOK * DMODEL * 2;
    const size_t OFF_VT = OFF_KB + (size_t)NTOK * DMODEL * 2;
    const size_t OFF_AO = OFF_VT + (size_t)NTOK * DMODEL * 2;
    const size_t OFF_OP = OFF_AO + (size_t)NTOK * DMODEL * 2;
    const size_t OFF_ML = OFF_OP + (size_t)512 * 2 * 128 * 64 * 4;   // 33.55 MB

    char* wsb = (char*)d_ws;
    int* flag = (int*)wsb;
    __hip_bfloat16* canon = (__hip_bfloat16*)(wsb + OFF_CANON);
    __hip_bfloat16* Xc = canon;
    __hip_bfloat16* Wq = Xc + N_X;
    __hip_bfloat16* Bq = Wq + N_WQ;
    __hip_bfloat16* Wo = Bq + N_BQ;
    __hip_bfloat16* Bo = Wo + N_WO;
    __hip_bfloat16* Qs = (__hip_bfloat16*)(wsb + OFF_QS);
    __hip_bfloat16* Kb = (__hip_bfloat16*)(wsb + OFF_KB);
    __hip_bfloat16* Vt = (__hip_bfloat16*)(wsb + OFF_VT);
    __hip_bfloat16* Ao = (__hip_bfloat16*)(wsb + OFF_AO);
    float* Opart = (float*)(wsb + OFF_OP);
    float* MLpart = (float*)(wsb + OFF_ML);

    // 0) dtype detect + canonicalize
    detect_kernel<<<1, 64, 0, stream>>>((const unsigned short*)d_in[1], flag);
    canon_kernel<<<(N_CANON + 255) / 256, 256, 0, stream>>>(
        d_in[0], d_in[1], d_in[2], d_in[3], d_in[4], canon, flag);

    // 1) QKV GEMM
    {
        dim3 grid(3 * DMODEL / 128, NTOK / 128);
        qkv_gemm_kernel<<<grid, 256, 0, stream>>>(Xc, Wq, Bq, Qs, Kb, Vt);
    }
    // 2) Attention: split-K pair-balanced, grid (16, B*H) = 512 WGs of 8
    //    waves; every WG exactly 17 chunks; 2 WGs/CU -> 4 waves/SIMD.
    {
        dim3 grid(16, BATCH * NHEAD);
        attn_kernel<<<grid, 512, 0, stream>>>(Qs, Kb, Vt, Opart, MLpart);
        attn_merge_kernel<<<(NTOK * NHEAD * 4) / 256, 256, 0, stream>>>(
            Opart, MLpart, Ao);
    }
    // 3) Out projection
    {
        dim3 grid(DMODEL / 128, NTOK / 128);
        proj_gemm_kernel<<<grid, 256, 0, stream>>>(Ao, Wo, Bo, d_out, flag);
    }
}

// Round 4
// 198.598 us; speedup vs baseline: 1.1703x; 1.0371x over previous
//
#include <hip/hip_runtime.h>
#include <hip/hip_bf16.h>

// Sizes (fixed): B=2, S=2048, D=1024, H=16, Hd=64
#define SEQ    2048
#define DMODEL 1024
#define NHEAD  16
#define HDIM   64
#define BATCH  2
#define NTOK   (BATCH * SEQ)           // 4096

#define N_X   (NTOK * DMODEL)
#define N_WQ  (3 * DMODEL * DMODEL)
#define N_BQ  (3 * DMODEL)
#define N_WO  (DMODEL * DMODEL)
#define N_BO  (DMODEL)
#define N_CANON (N_X + N_WQ + N_BQ + N_WO + N_BO)   // 8,392,704

#define NEG_SENT (-1.0e30f)
#define QSCALE 0.1803368801111f        // (1/8) * log2(e)

typedef __attribute__((ext_vector_type(8))) short short8;
typedef __attribute__((ext_vector_type(4))) short short4v;
typedef __attribute__((ext_vector_type(4))) float f32x4;

#define MFMA_BF16(A, B, C) __builtin_amdgcn_mfma_f32_16x16x32_bf16((A), (B), (C), 0, 0, 0)

static __device__ __forceinline__ short8 load8(const __hip_bfloat16* p) {
    return *(const short8*)p;
}

static __device__ __forceinline__ void async16(const void* g, void* l) {
    __builtin_amdgcn_global_load_lds(
        (const __attribute__((address_space(1))) unsigned int*)g,
        (__attribute__((address_space(3))) unsigned int*)l,
        16, 0, 0);
}

// ---------------------------------------------------------------------------
// Kernel 0: dtype detector (confirmed fp32 in round 2; keep for robustness)
// ---------------------------------------------------------------------------
__global__ void detect_kernel(const unsigned short* __restrict__ w, int* flag) {
    int cnt = 0;
    for (int i = threadIdx.x; i < 512; i += 64) {
        const unsigned e = (w[i] >> 7) & 0xFF;
        if (e >= 125) cnt++;
    }
#pragma unroll
    for (int o = 32; o; o >>= 1) cnt += __shfl_down(cnt, o);
    if (threadIdx.x == 0) *flag = (cnt > 8) ? 1 : 0;
}

// ---------------------------------------------------------------------------
// Kernel 0b: canonicalize inputs to bf16: [X | Wqkv | bqkv | Wout | bout]
// ---------------------------------------------------------------------------
__global__ __launch_bounds__(256) void canon_kernel(
    const void* __restrict__ s0, const void* __restrict__ s1,
    const void* __restrict__ s2, const void* __restrict__ s3,
    const void* __restrict__ s4,
    __hip_bfloat16* __restrict__ dst, const int* __restrict__ flag)
{
    const int idx = blockIdx.x * 256 + threadIdx.x;
    if (idx >= N_CANON) return;
    const void* src;
    int off;
    if (idx < N_X)                         { src = s0; off = idx; }
    else if (idx < N_X + N_WQ)             { src = s1; off = idx - N_X; }
    else if (idx < N_X + N_WQ + N_BQ)      { src = s2; off = idx - (N_X + N_WQ); }
    else if (idx < N_X + N_WQ + N_BQ + N_WO){ src = s3; off = idx - (N_X + N_WQ + N_BQ); }
    else                                   { src = s4; off = idx - (N_X + N_WQ + N_BQ + N_WO); }
    const bool isf32 = (*flag != 0);
    const float v = isf32 ? ((const float*)src)[off]
                          : __bfloat162float(((const __hip_bfloat16*)src)[off]);
    dst[idx] = __float2bfloat16(v);
}

// ---------------------------------------------------------------------------
// Kernel 1: QKV GEMM, m97 structure + double-buffered staging (counted vmcnt).
// (unchanged from round 12)
// ---------------------------------------------------------------------------
__global__ __launch_bounds__(256) void qkv_gemm_kernel(
    const __hip_bfloat16* __restrict__ X,
    const __hip_bfloat16* __restrict__ W,
    const __hip_bfloat16* __restrict__ bias,
    __hip_bfloat16* __restrict__ Qs,
    __hip_bfloat16* __restrict__ Kb,
    __hip_bfloat16* __restrict__ Vt)
{
    constexpr int Kd = DMODEL;
    __shared__ __align__(16) __hip_bfloat16 As[2][128 * 32];
    __shared__ __align__(16) __hip_bfloat16 Bs[2][128 * 32];

    const int tid   = threadIdx.x;
    const int lane  = tid & 63;
    const int w     = tid >> 6;
    const int mTile = blockIdx.y * 128;
    const int nTile = blockIdx.x * 128;
    const int wm    = (w >> 1) * 64;
    const int wn    = (w & 1) * 64;
    const int lm    = lane & 15;
    const int lk    = (lane >> 4) * 8;

    f32x4 acc[4][4];
#pragma unroll
    for (int i = 0; i < 4; ++i)
#pragma unroll
        for (int j = 0; j < 4; ++j)
            acc[i][j] = (f32x4){0.f, 0.f, 0.f, 0.f};

    const int r0c = tid >> 2, p0c = tid & 3;
    const int r1c = (tid + 256) >> 2;

    const __hip_bfloat16* gA0 = &X[(size_t)(mTile + r0c) * Kd + p0c * 8];
    const __hip_bfloat16* gA1 = &X[(size_t)(mTile + r1c) * Kd + p0c * 8];
    const __hip_bfloat16* gB0 = &W[(size_t)(nTile + r0c) * Kd + p0c * 8];
    const __hip_bfloat16* gB1 = &W[(size_t)(nTile + r1c) * Kd + p0c * 8];

    // prologue: stage k0=0 into buffer 0
    async16(gA0, (char*)As[0] + tid * 16);
    async16(gA1, (char*)As[0] + tid * 16 + 4096);
    async16(gB0, (char*)Bs[0] + tid * 16);
    async16(gB1, (char*)Bs[0] + tid * 16 + 4096);

    int cur = 0;
    constexpr int NIT = Kd / 32;
    for (int it = 0; it < NIT; ++it) {
        if (it + 1 < NIT) {
            const int k1 = (it + 1) * 32;
            async16(gA0 + k1, (char*)As[cur ^ 1] + tid * 16);
            async16(gA1 + k1, (char*)As[cur ^ 1] + tid * 16 + 4096);
            async16(gB0 + k1, (char*)Bs[cur ^ 1] + tid * 16);
            async16(gB1 + k1, (char*)Bs[cur ^ 1] + tid * 16 + 4096);
            asm volatile("s_waitcnt vmcnt(4)" ::: "memory");
        } else {
            asm volatile("s_waitcnt vmcnt(0)" ::: "memory");
        }
        __builtin_amdgcn_s_barrier();          // buf[cur] visible to all waves
        __builtin_amdgcn_sched_barrier(0);

        const __hip_bfloat16* Ac = As[cur];
        const __hip_bfloat16* Bc = Bs[cur];
        short8 a[4], b[4];
#pragma unroll
        for (int i = 0; i < 4; ++i)
            a[i] = *(const short8*)&Ac[(wm + i * 16 + lm) * 32 + lk];
#pragma unroll
        for (int j = 0; j < 4; ++j)
            b[j] = *(const short8*)&Bc[(wn + j * 16 + lm) * 32 + lk];
#pragma unroll
        for (int i = 0; i < 4; ++i)
#pragma unroll
            for (int j = 0; j < 4; ++j)
                acc[i][j] = MFMA_BF16(a[i], b[j], acc[i][j]);

        __builtin_amdgcn_s_barrier();          // all waves done reading buf[cur]
        cur ^= 1;
    }

    const int r0 = (lane >> 4) * 4;
#pragma unroll
    for (int j = 0; j < 4; ++j) {
        const int n  = nTile + wn + j * 16 + lm;
        const float bv = __bfloat162float(bias[n]);
        const int c = n >> 10;
        const int h = (n >> 6) & 15;
        const int d = n & 63;
#pragma unroll
        for (int i = 0; i < 4; ++i) {
            if (c == 2) {
                // V: 4 consecutive s per thread -> one packed 8B store
                const int m0 = mTile + wm + i * 16 + r0;
                const int bb = m0 >> 11;
                const int s0 = m0 & (SEQ - 1);
                const int bh = bb * NHEAD + h;
                short4v pk;
#pragma unroll
                for (int r = 0; r < 4; ++r)
                    pk[r] = (short)__bfloat16_as_ushort(
                        __float2bfloat16(acc[i][j][r] + bv));
                *(short4v*)&Vt[(size_t)(bh * HDIM + d) * SEQ + s0] = pk;
            } else {
#pragma unroll
                for (int r = 0; r < 4; ++r) {
                    const int m  = mTile + wm + i * 16 + r0 + r;
                    const int bb = m >> 11;
                    const int s  = m & (SEQ - 1);
                    const int bh = bb * NHEAD + h;
                    const float v = acc[i][j][r] + bv;
                    if (c == 0) {
                        Qs[(size_t)(bh * SEQ + s) * HDIM + d] = __float2bfloat16(v * QSCALE);
                    } else {
                        Kb[(size_t)(bh * SEQ + s) * HDIM + d] = __float2bfloat16(v);
                    }
                }
            }
        }
    }
}

// ---------------------------------------------------------------------------
// Kernel 2: cooperative causal flash attention, SPLIT-K pair-balanced,
// 3-STAGE RING BUFFER, one barrier per chunk.
//
// Round-13 change vs round 12 (48.4 us, VALUBusy 50%, MfmaUtil 14%):
// the 2-barrier-per-chunk structure made all 8 waves rendezvous twice per
// 64 keys (~36% of time in sync dead space).  With 3 K/V stages (48KB +
// 18KB P = 66KB, still 2 WGs/CU), stage target at iter c is buf[(c+2)%3],
// last read at iter c-1 -> a single barrier at the top of each iteration
// suffices:  vmcnt(2) -> s_barrier -> issue stage(c+2) -> compute(c).
// Staging issue overlaps compute; barrier count halves (34 -> 17 per WG).
// ---------------------------------------------------------------------------
#define P_PITCH 72
__global__ __launch_bounds__(512, 4) void attn_kernel(
    const __hip_bfloat16* __restrict__ Qs,  // [B,H,S,Hd], pre-scaled
    const __hip_bfloat16* __restrict__ Kb,  // [B,H,S,Hd]
    const __hip_bfloat16* __restrict__ Vt,  // [B,H,Hd,S]
    float* __restrict__ Opart,              // [512 wg][2 ph][128][64] f32
    float* __restrict__ MLpart)             // [512 wg][2 ph][128][2] f32
{
    __shared__ __align__(16) __hip_bfloat16 Kt[3][64 * 64];
    __shared__ __align__(16) __hip_bfloat16 Vs[3][64 * 64];
    __shared__ __align__(16) __hip_bfloat16 Pall[8][16 * P_PITCH];

    const int tid  = threadIdx.x;
    const int lane = tid & 63;
    const int wv   = tid >> 6;              // 0..7
    const int p    = blockIdx.x >> 1;       // pair index 0..7
    const int kh   = blockIdx.x & 1;        // key-range half 0/1
    const int bh   = blockIdx.y;
    const int wgid = bh * 16 + blockIdx.x;

    const int lm  = lane & 15;
    const int q4  = lane >> 4;
    const int lk  = q4 * 8;
    const int swz = (lm & 3) << 4;

    __hip_bfloat16* P = Pall[wv];

    const __hip_bfloat16* Qbh = Qs + (size_t)bh * SEQ * HDIM;
    const __hip_bfloat16* Kbh = Kb + (size_t)bh * SEQ * HDIM;
    const __hip_bfloat16* Vbh = Vt + (size_t)bh * HDIM * SEQ;

    // staging address components: 512 threads, 8 threads x 16B per 128B row
    const int srow = tid >> 3;              // 0..63 (k-row for Kt, d-row for Vs)
    const int scb  = (tid & 7) ^ (srow & 7);   // XOR-swizzled column block

    for (int ph = 0; ph < 2; ++ph) {
        const int qb    = ph ? p : 15 - p;     // heavy first, then light
        const int wbase = qb * 128 + wv * 16;  // this wave's 16 q-rows
        const int nCh   = qb + 1;              // chunks this WG handles
        const int c0    = kh * nCh;            // first global chunk index

        short8 qa[2];
#pragma unroll
        for (int h = 0; h < 2; ++h)
            qa[h] = load8(&Qbh[(size_t)(wbase + lm) * HDIM + h * 32 + lk]);

        float m_run = NEG_SENT;
        float l_run = 0.f;
        f32x4 Oacc[4];
#pragma unroll
        for (int t = 0; t < 4; ++t) Oacc[t] = (f32x4){0.f, 0.f, 0.f, 0.f};

        // protect ring buffers from the previous phase's in-flight compute
        __builtin_amdgcn_s_barrier();

        // prologue: stage first (up to) two chunks into slots 0,1
        {
            const int kk0 = c0 * 64;
            async16(&Kbh[(size_t)(kk0 + srow) * HDIM + scb * 8], (char*)Kt[0] + tid * 16);
            async16(&Vbh[(size_t)srow * SEQ + kk0 + scb * 8],    (char*)Vs[0] + tid * 16);
            if (nCh >= 2) {
                const int kk1 = kk0 + 64;
                async16(&Kbh[(size_t)(kk1 + srow) * HDIM + scb * 8], (char*)Kt[1] + tid * 16);
                async16(&Vbh[(size_t)srow * SEQ + kk1 + scb * 8],    (char*)Vs[1] + tid * 16);
            }
        }

        int cur = 0;
        for (int ci = 0; ci < nCh; ++ci) {
            const int k0 = (c0 + ci) * 64;

            if (ci + 1 < nCh) {
                // wait until only chunk ci+1's 2 loads remain -> ci's done
                asm volatile("s_waitcnt vmcnt(2)" ::: "memory");
            } else {
                asm volatile("s_waitcnt vmcnt(0)" ::: "memory");
            }
            __builtin_amdgcn_s_barrier();          // everyone done with buf[(ci+2)%3]
            __builtin_amdgcn_sched_barrier(0);

            if (ci + 2 < nCh) {                    // stage chunk ci+2 (overlaps compute)
                const int slot = (cur + 2 >= 3) ? cur - 1 : cur + 2;
                const int kk = (c0 + ci + 2) * 64;
                async16(&Kbh[(size_t)(kk + srow) * HDIM + scb * 8], (char*)Kt[slot] + tid * 16);
                async16(&Vbh[(size_t)srow * SEQ + kk + scb * 8],    (char*)Vs[slot] + tid * 16);
            }

            if (k0 <= wbase + 15) {   // not fully masked for this wave
                const __hip_bfloat16* Kc = Kt[cur];
                const __hip_bfloat16* Vc = Vs[cur];

                short8 ka[4][2];
#pragma unroll
                for (int t = 0; t < 4; ++t)
#pragma unroll
                    for (int h = 0; h < 2; ++h)
                        ka[t][h] = *(const short8*)&Kc[(t * 16 + lm) * 64 +
                                                       (((h * 4 + q4) ^ (lm & 7)) * 8)];

                f32x4 sc[4];
#pragma unroll
                for (int t = 0; t < 4; ++t) sc[t] = (f32x4){0.f, 0.f, 0.f, 0.f};
#pragma unroll
                for (int t = 0; t < 4; ++t) {
                    sc[t] = MFMA_BF16(ka[t][0], qa[0], sc[t]);
                    sc[t] = MFMA_BF16(ka[t][1], qa[1], sc[t]);
                }

                if (k0 + 63 > wbase) {
                    const int row = wbase + lm;
#pragma unroll
                    for (int t = 0; t < 4; ++t)
#pragma unroll
                        for (int r = 0; r < 4; ++r) {
                            const int key = k0 + t * 16 + q4 * 4 + r;
                            if (key > row) sc[t][r] = NEG_SENT;
                        }
                }

                // online softmax (scores for q-row lm live in this lane)
                float mx = sc[0][0];
#pragma unroll
                for (int t = 0; t < 4; ++t)
#pragma unroll
                    for (int r = 0; r < 4; ++r) mx = fmaxf(mx, sc[t][r]);
                mx = fmaxf(mx, __shfl_xor(mx, 16));
                mx = fmaxf(mx, __shfl_xor(mx, 32));

                // defer-max (T13): only rescale when max grew by > 8 (log2)
                if (!__all(mx <= m_run + 8.0f)) {
                    const float mn = fmaxf(m_run, mx);
                    const float alpha = exp2f(m_run - mn);
                    m_run = mn;
                    l_run *= alpha;
#pragma unroll
                    for (int r = 0; r < 4; ++r) {
                        const float av = __shfl(alpha, q4 * 4 + r);
#pragma unroll
                        for (int t = 0; t < 4; ++t) Oacc[t][r] *= av;
                    }
                }

                float s = 0.f;
#pragma unroll
                for (int t = 0; t < 4; ++t)
#pragma unroll
                    for (int r = 0; r < 4; ++r) {
                        const float pv = exp2f(sc[t][r] - m_run);
                        sc[t][r] = pv;
                        s += pv;
                    }
                s += __shfl_xor(s, 16);
                s += __shfl_xor(s, 32);
                l_run += s;

#pragma unroll
                for (int t = 0; t < 4; ++t) {
                    short4v pk;
#pragma unroll
                    for (int r = 0; r < 4; ++r)
                        pk[r] = (short)__bfloat16_as_ushort(__float2bfloat16(sc[t][r]));
                    const int col = (t * 16 + q4 * 4) ^ swz;
                    *(short4v*)&P[lm * P_PITCH + col] = pk;
                }

#pragma unroll
                for (int h = 0; h < 2; ++h) {
                    const short8 pa = *(const short8*)&P[lm * P_PITCH + ((h * 32 + lk) ^ swz)];
#pragma unroll
                    for (int t = 0; t < 4; ++t) {
                        const short8 vb = *(const short8*)&Vc[(t * 16 + lm) * 64 +
                                                              (((h * 4 + q4) ^ (lm & 7)) * 8)];
                        Oacc[t] = MFMA_BF16(pa, vb, Oacc[t]);
                    }
                }
            }

            cur = (cur + 1 == 3) ? 0 : cur + 1;
        }

        // --- epilogue: store f32 partials for this phase's 16 rows/wave ---
        const size_t pbase = ((size_t)wgid * 2 + ph) * 128;
#pragma unroll
        for (int t = 0; t < 4; ++t)
#pragma unroll
            for (int r = 0; r < 4; ++r)
                Opart[(pbase + wv * 16 + q4 * 4 + r) * 64 + t * 16 + lm] = Oacc[t][r];
        if (lane < 16) {
            MLpart[(pbase + wv * 16 + lane) * 2 + 0] = m_run;
            MLpart[(pbase + wv * 16 + lane) * 2 + 1] = l_run;
        }
    }
}

// ---------------------------------------------------------------------------
// Kernel 2b: merge the two key-half partials per row, normalize, write bf16.
// One thread per (row, 16-d group): 32bh * 2048s * 4 = 262144 threads.
// ---------------------------------------------------------------------------
__global__ __launch_bounds__(256) void attn_merge_kernel(
    const float* __restrict__ Opart, const float* __restrict__ MLpart,
    __hip_bfloat16* __restrict__ O)
{
    const int idx  = blockIdx.x * 256 + threadIdx.x;
    const int d16  = idx & 3;
    const int grow = idx >> 2;             // bh*2048 + s
    const int bh   = grow >> 11;
    const int s    = grow & 2047;
    const int qb   = s >> 7;
    const int rin  = s & 127;
    const int p    = (qb >= 8) ? (15 - qb) : qb;
    const int ph   = (qb >= 8) ? 0 : 1;
    const size_t r0 = ((size_t)(bh * 16 + p * 2 + 0) * 2 + ph) * 128 + rin;
    const size_t r1 = ((size_t)(bh * 16 + p * 2 + 1) * 2 + ph) * 128 + rin;

    const float m1 = MLpart[r0 * 2], l1 = MLpart[r0 * 2 + 1];
    const float m2 = MLpart[r1 * 2], l2 = MLpart[r1 * 2 + 1];
    const float mm = fmaxf(m1, m2);
    const float a1 = exp2f(m1 - mm), a2 = exp2f(m2 - mm);
    const float inv = 1.0f / (a1 * l1 + a2 * l2);

    const f32x4* O1 = (const f32x4*)&Opart[r0 * 64 + d16 * 16];
    const f32x4* O2 = (const f32x4*)&Opart[r1 * 64 + d16 * 16];

    short8 out[2];
#pragma unroll
    for (int v = 0; v < 4; ++v) {
        const f32x4 x1 = O1[v], x2 = O2[v];
#pragma unroll
        for (int j = 0; j < 4; ++j)
            out[v >> 1][(v & 1) * 4 + j] = (short)__bfloat16_as_ushort(
                __float2bfloat16((a1 * x1[j] + a2 * x2[j]) * inv));
    }
    const int b = bh >> 4, hh = bh & 15;
    __hip_bfloat16* dst = &O[((size_t)b * SEQ + s) * DMODEL + hh * 64 + d16 * 16];
    ((short8*)dst)[0] = out[0];
    ((short8*)dst)[1] = out[1];
}

// ---------------------------------------------------------------------------
// Kernel 3: out projection, 128x64 tiles (512 WGs = 2 WGs/CU, was 1/CU),
// double-buffered staging with counted vmcnt.
// ---------------------------------------------------------------------------
__global__ __launch_bounds__(256) void proj_gemm_kernel(
    const __hip_bfloat16* __restrict__ A,
    const __hip_bfloat16* __restrict__ W,
    const __hip_bfloat16* __restrict__ bias,
    void* __restrict__ outv,
    const int* __restrict__ flag)
{
    constexpr int Kd = DMODEL;
    __shared__ __align__(16) __hip_bfloat16 As[2][128 * 32];
    __shared__ __align__(16) __hip_bfloat16 Bs[2][64 * 32];

    const int tid   = threadIdx.x;
    const int lane  = tid & 63;
    const int w     = tid >> 6;
    const int mTile = blockIdx.y * 128;
    const int nTile = blockIdx.x * 64;
    const int wm    = (w >> 1) * 64;
    const int wn    = (w & 1) * 32;
    const int lm    = lane & 15;
    const int lk    = (lane >> 4) * 8;
    const bool f32out = (*flag != 0);

    f32x4 acc[4][2];
#pragma unroll
    for (int i = 0; i < 4; ++i)
#pragma unroll
        for (int j = 0; j < 2; ++j)
            acc[i][j] = (f32x4){0.f, 0.f, 0.f, 0.f};

    const int r0c = tid >> 2, p0c = tid & 3;
    const int r1c = (tid + 256) >> 2;

    const __hip_bfloat16* gA0 = &A[(size_t)(mTile + r0c) * Kd + p0c * 8];
    const __hip_bfloat16* gA1 = &A[(size_t)(mTile + r1c) * Kd + p0c * 8];
    const __hip_bfloat16* gB0 = &W[(size_t)(nTile + r0c) * Kd + p0c * 8];

    async16(gA0, (char*)As[0] + tid * 16);
    async16(gA1, (char*)As[0] + tid * 16 + 4096);
    async16(gB0, (char*)Bs[0] + tid * 16);

    int cur = 0;
    constexpr int NIT = Kd / 32;
    for (int it = 0; it < NIT; ++it) {
        if (it + 1 < NIT) {
            const int k1 = (it + 1) * 32;
            async16(gA0 + k1, (char*)As[cur ^ 1] + tid * 16);
            async16(gA1 + k1, (char*)As[cur ^ 1] + tid * 16 + 4096);
            async16(gB0 + k1, (char*)Bs[cur ^ 1] + tid * 16);
            asm volatile("s_waitcnt vmcnt(3)" ::: "memory");
        } else {
            asm volatile("s_waitcnt vmcnt(0)" ::: "memory");
        }
        __builtin_amdgcn_s_barrier();
        __builtin_amdgcn_sched_barrier(0);

        const __hip_bfloat16* Ac = As[cur];
        const __hip_bfloat16* Bc = Bs[cur];
        short8 a[4], b[2];
#pragma unroll
        for (int i = 0; i < 4; ++i)
            a[i] = *(const short8*)&Ac[(wm + i * 16 + lm) * 32 + lk];
#pragma unroll
        for (int j = 0; j < 2; ++j)
            b[j] = *(const short8*)&Bc[(wn + j * 16 + lm) * 32 + lk];
#pragma unroll
        for (int i = 0; i < 4; ++i)
#pragma unroll
            for (int j = 0; j < 2; ++j)
                acc[i][j] = MFMA_BF16(a[i], b[j], acc[i][j]);

        __builtin_amdgcn_s_barrier();
        cur ^= 1;
    }

    const int r0 = (lane >> 4) * 4;
#pragma unroll
    for (int j = 0; j < 2; ++j) {
        const int n = nTile + wn + j * 16 + lm;
        const float bv = __bfloat162float(bias[n]);
#pragma unroll
        for (int i = 0; i < 4; ++i) {
#pragma unroll
            for (int r = 0; r < 4; ++r) {
                const size_t m = mTile + wm + i * 16 + r0 + r;
                const float v = acc[i][j][r] + bv;
                if (f32out) ((float*)outv)[m * DMODEL + n] = v;
                else ((__hip_bfloat16*)outv)[m * DMODEL + n] = __float2bfloat16(v);
            }
        }
    }
}

// ---------------------------------------------------------------------------
extern "C" void kernel_launch(void* const* d_in, const int* in_sizes, int n_in,
                              void* d_out, int out_size, void* d_ws, size_t ws_size,
                              hipStream_t stream) {
    // Workspace layout (bytes):
    // [flag:256][canon bf16][Qs][Kb][Vt][Ao][Opart f32][MLpart f32]
    const size_t OFF_CANON = 256;
    const size_t OFF_QS = OFF_CANON + (size_t)N_CANON * 2;
    const size_t OFF_KB = OFF_QS + (size_t)NTOK * DMODEL * 2;
    const size_t OFF_VT = OFF_KB + (size_t)NTOK * DMODEL * 2;
    const size_t OFF_AO = OFF_VT + (size_t)NTOK * DMODEL * 2;
    const size_t OFF_OP = OFF_AO + (size_t)NTOK * DMODEL * 2;
    const size_t OFF_ML = OFF_OP + (size_t)512 * 2 * 128 * 64 * 4;   // 33.55 MB

    char* wsb = (char*)d_ws;
    int* flag = (int*)wsb;
    __hip_bfloat16* canon = (__hip_bfloat16*)(wsb + OFF_CANON);
    __hip_bfloat16* Xc = canon;
    __hip_bfloat16* Wq = Xc + N_X;
    __hip_bfloat16* Bq = Wq + N_WQ;
    __hip_bfloat16* Wo = Bq + N_BQ;
    __hip_bfloat16* Bo = Wo + N_WO;
    __hip_bfloat16* Qs = (__hip_bfloat16*)(wsb + OFF_QS);
    __hip_bfloat16* Kb = (__hip_bfloat16*)(wsb + OFF_KB);
    __hip_bfloat16* Vt = (__hip_bfloat16*)(wsb + OFF_VT);
    __hip_bfloat16* Ao = (__hip_bfloat16*)(wsb + OFF_AO);
    float* Opart = (float*)(wsb + OFF_OP);
    float* MLpart = (float*)(wsb + OFF_ML);

    // 0) dtype detect + canonicalize
    detect_kernel<<<1, 64, 0, stream>>>((const unsigned short*)d_in[1], flag);
    canon_kernel<<<(N_CANON + 255) / 256, 256, 0, stream>>>(
        d_in[0], d_in[1], d_in[2], d_in[3], d_in[4], canon, flag);

    // 1) QKV GEMM
    {
        dim3 grid(3 * DMODEL / 128, NTOK / 128);
        qkv_gemm_kernel<<<grid, 256, 0, stream>>>(Xc, Wq, Bq, Qs, Kb, Vt);
    }
    // 2) Attention: split-K pair-balanced, grid (16, B*H) = 512 WGs of 8
    //    waves; every WG exactly 17 chunks; 2 WGs/CU -> 4 waves/SIMD.
    {
        dim3 grid(16, BATCH * NHEAD);
        attn_kernel<<<grid, 512, 0, stream>>>(Qs, Kb, Vt, Opart, MLpart);
        attn_merge_kernel<<<(NTOK * NHEAD * 4) / 256, 256, 0, stream>>>(
            Opart, MLpart, Ao);
    }
    // 3) Out projection: 128x64 tiles -> 512 WGs (2 WGs/CU)
    {
        dim3 grid(DMODEL / 64, NTOK / 128);
        proj_gemm_kernel<<<grid, 256, 0, stream>>>(Ao, Wo, Bo, d_out, flag);
    }
}

// Round 5
// 192.174 us; speedup vs baseline: 1.2094x; 1.0334x over previous
//
#include <hip/hip_runtime.h>
#include <hip/hip_bf16.h>

// Sizes (fixed): B=2, S=2048, D=1024, H=16, Hd=64
#define SEQ    2048
#define DMODEL 1024
#define NHEAD  16
#define HDIM   64
#define BATCH  2
#define NTOK   (BATCH * SEQ)           // 4096

#define N_X   (NTOK * DMODEL)
#define N_WQ  (3 * DMODEL * DMODEL)
#define N_BQ  (3 * DMODEL)
#define N_WO  (DMODEL * DMODEL)
#define N_BO  (DMODEL)
#define N_CANON (N_X + N_WQ + N_BQ + N_WO + N_BO)   // 8,392,704

#define NEG_SENT (-1.0e30f)
#define QSCALE 0.1803368801111f        // (1/8) * log2(e)

typedef __attribute__((ext_vector_type(8))) short short8;
typedef __attribute__((ext_vector_type(4))) short short4v;
typedef __attribute__((ext_vector_type(4))) float f32x4;

#define MFMA_BF16(A, B, C) __builtin_amdgcn_mfma_f32_16x16x32_bf16((A), (B), (C), 0, 0, 0)

static __device__ __forceinline__ short8 load8(const __hip_bfloat16* p) {
    return *(const short8*)p;
}

static __device__ __forceinline__ void async16(const void* g, void* l) {
    __builtin_amdgcn_global_load_lds(
        (const __attribute__((address_space(1))) unsigned int*)g,
        (__attribute__((address_space(3))) unsigned int*)l,
        16, 0, 0);
}

// ---------------------------------------------------------------------------
// Kernel 0: dtype detector (confirmed fp32 in round 2; keep for robustness)
// ---------------------------------------------------------------------------
__global__ void detect_kernel(const unsigned short* __restrict__ w, int* flag) {
    int cnt = 0;
    for (int i = threadIdx.x; i < 512; i += 64) {
        const unsigned e = (w[i] >> 7) & 0xFF;
        if (e >= 125) cnt++;
    }
#pragma unroll
    for (int o = 32; o; o >>= 1) cnt += __shfl_down(cnt, o);
    if (threadIdx.x == 0) *flag = (cnt > 8) ? 1 : 0;
}

// ---------------------------------------------------------------------------
// Kernel 0b: canonicalize inputs to bf16, VECTORIZED 8 elems/thread.
// All segment boundaries are multiples of 8, so one thread's 8 elements
// stay within a single source tensor.
// ---------------------------------------------------------------------------
__global__ __launch_bounds__(256) void canon_kernel(
    const void* __restrict__ s0, const void* __restrict__ s1,
    const void* __restrict__ s2, const void* __restrict__ s3,
    const void* __restrict__ s4,
    __hip_bfloat16* __restrict__ dst, const int* __restrict__ flag)
{
    const int v = blockIdx.x * 256 + threadIdx.x;
    if (v >= N_CANON / 8) return;
    const int idx = v * 8;
    const void* src;
    int off;
    if (idx < N_X)                          { src = s0; off = idx; }
    else if (idx < N_X + N_WQ)              { src = s1; off = idx - N_X; }
    else if (idx < N_X + N_WQ + N_BQ)       { src = s2; off = idx - (N_X + N_WQ); }
    else if (idx < N_X + N_WQ + N_BQ + N_WO){ src = s3; off = idx - (N_X + N_WQ + N_BQ); }
    else                                    { src = s4; off = idx - (N_X + N_WQ + N_BQ + N_WO); }
    if (*flag != 0) {
        const f32x4* sp = (const f32x4*)((const float*)src + off);
        const f32x4 x0 = sp[0], x1 = sp[1];
        short8 o;
#pragma unroll
        for (int j = 0; j < 4; ++j) {
            o[j]     = (short)__bfloat16_as_ushort(__float2bfloat16(x0[j]));
            o[4 + j] = (short)__bfloat16_as_ushort(__float2bfloat16(x1[j]));
        }
        *(short8*)&dst[idx] = o;
    } else {
        *(short8*)&dst[idx] = *(const short8*)((const __hip_bfloat16*)src + off);
    }
}

// ---------------------------------------------------------------------------
// Kernel 1: QKV GEMM, m97 structure + double-buffered staging (counted vmcnt)
// + T2 LDS swizzle (round 14): the linear [row][32] tile (64B rows) was an
// 8-way bank conflict on ds_read_b128 (3.15M conflict cycles).  Fix per
// rule #21: LDS dest stays LINEAR; the GLOBAL source column-block is
// pre-swizzled (cb ^= (row>>1)&3) and the read side XORs the same.
// 8-way -> 2-way (free, m136).
// ---------------------------------------------------------------------------
__global__ __launch_bounds__(256) void qkv_gemm_kernel(
    const __hip_bfloat16* __restrict__ X,
    const __hip_bfloat16* __restrict__ W,
    const __hip_bfloat16* __restrict__ bias,
    __hip_bfloat16* __restrict__ Qs,
    __hip_bfloat16* __restrict__ Kb,
    __hip_bfloat16* __restrict__ Vt)
{
    constexpr int Kd = DMODEL;
    __shared__ __align__(16) __hip_bfloat16 As[2][128 * 32];
    __shared__ __align__(16) __hip_bfloat16 Bs[2][128 * 32];

    const int tid   = threadIdx.x;
    const int lane  = tid & 63;
    const int w     = tid >> 6;
    const int mTile = blockIdx.y * 128;
    const int nTile = blockIdx.x * 128;
    const int wm    = (w >> 1) * 64;
    const int wn    = (w & 1) * 64;
    const int lm    = lane & 15;
    const int q4    = lane >> 4;
    // swizzled read column block: q4 ^ ((row>>1)&3); row = wm+i*16+lm ->
    // (row>>1)&3 == (lm>>1)&3 (wm+i*16 multiple of 16)
    const int lks   = (q4 ^ ((lm >> 1) & 3)) * 8;

    f32x4 acc[4][4];
#pragma unroll
    for (int i = 0; i < 4; ++i)
#pragma unroll
        for (int j = 0; j < 4; ++j)
            acc[i][j] = (f32x4){0.f, 0.f, 0.f, 0.f};

    const int r0c = tid >> 2;
    const int r1c = (tid + 256) >> 2;
    // pre-swizzled global column block; (r0c>>1)&3 == (tid>>3)&3, and the
    // second half (r1c = 64 + tid>>2) gives the same value (64>>1 = 32, &3=0)
    const int cbs = ((tid & 3) ^ ((tid >> 3) & 3)) * 8;

    const __hip_bfloat16* gA0 = &X[(size_t)(mTile + r0c) * Kd + cbs];
    const __hip_bfloat16* gA1 = &X[(size_t)(mTile + r1c) * Kd + cbs];
    const __hip_bfloat16* gB0 = &W[(size_t)(nTile + r0c) * Kd + cbs];
    const __hip_bfloat16* gB1 = &W[(size_t)(nTile + r1c) * Kd + cbs];

    // prologue: stage k0=0 into buffer 0
    async16(gA0, (char*)As[0] + tid * 16);
    async16(gA1, (char*)As[0] + tid * 16 + 4096);
    async16(gB0, (char*)Bs[0] + tid * 16);
    async16(gB1, (char*)Bs[0] + tid * 16 + 4096);

    int cur = 0;
    constexpr int NIT = Kd / 32;
    for (int it = 0; it < NIT; ++it) {
        if (it + 1 < NIT) {
            const int k1 = (it + 1) * 32;
            async16(gA0 + k1, (char*)As[cur ^ 1] + tid * 16);
            async16(gA1 + k1, (char*)As[cur ^ 1] + tid * 16 + 4096);
            async16(gB0 + k1, (char*)Bs[cur ^ 1] + tid * 16);
            async16(gB1 + k1, (char*)Bs[cur ^ 1] + tid * 16 + 4096);
            asm volatile("s_waitcnt vmcnt(4)" ::: "memory");
        } else {
            asm volatile("s_waitcnt vmcnt(0)" ::: "memory");
        }
        __builtin_amdgcn_s_barrier();          // buf[cur] visible to all waves
        __builtin_amdgcn_sched_barrier(0);

        const __hip_bfloat16* Ac = As[cur];
        const __hip_bfloat16* Bc = Bs[cur];
        short8 a[4], b[4];
#pragma unroll
        for (int i = 0; i < 4; ++i)
            a[i] = *(const short8*)&Ac[(wm + i * 16 + lm) * 32 + lks];
#pragma unroll
        for (int j = 0; j < 4; ++j)
            b[j] = *(const short8*)&Bc[(wn + j * 16 + lm) * 32 + lks];
#pragma unroll
        for (int i = 0; i < 4; ++i)
#pragma unroll
            for (int j = 0; j < 4; ++j)
                acc[i][j] = MFMA_BF16(a[i], b[j], acc[i][j]);

        __builtin_amdgcn_s_barrier();          // all waves done reading buf[cur]
        cur ^= 1;
    }

    const int r0 = (lane >> 4) * 4;
#pragma unroll
    for (int j = 0; j < 4; ++j) {
        const int n  = nTile + wn + j * 16 + lm;
        const float bv = __bfloat162float(bias[n]);
        const int c = n >> 10;
        const int h = (n >> 6) & 15;
        const int d = n & 63;
#pragma unroll
        for (int i = 0; i < 4; ++i) {
            if (c == 2) {
                // V: 4 consecutive s per thread -> one packed 8B store
                const int m0 = mTile + wm + i * 16 + r0;
                const int bb = m0 >> 11;
                const int s0 = m0 & (SEQ - 1);
                const int bh = bb * NHEAD + h;
                short4v pk;
#pragma unroll
                for (int r = 0; r < 4; ++r)
                    pk[r] = (short)__bfloat16_as_ushort(
                        __float2bfloat16(acc[i][j][r] + bv));
                *(short4v*)&Vt[(size_t)(bh * HDIM + d) * SEQ + s0] = pk;
            } else {
#pragma unroll
                for (int r = 0; r < 4; ++r) {
                    const int m  = mTile + wm + i * 16 + r0 + r;
                    const int bb = m >> 11;
                    const int s  = m & (SEQ - 1);
                    const int bh = bb * NHEAD + h;
                    const float v = acc[i][j][r] + bv;
                    if (c == 0) {
                        Qs[(size_t)(bh * SEQ + s) * HDIM + d] = __float2bfloat16(v * QSCALE);
                    } else {
                        Kb[(size_t)(bh * SEQ + s) * HDIM + d] = __float2bfloat16(v);
                    }
                }
            }
        }
    }
}

// ---------------------------------------------------------------------------
// Kernel 2: cooperative causal flash attention, SPLIT-K pair-balanced,
// 3-stage ring buffer + T5 setprio around MFMA clusters (round 14).
// attn is ~80% issue-bound now; setprio is the per-instruction lever
// (measured +4-7% on attn, m191).
// ---------------------------------------------------------------------------
#define P_PITCH 72
__global__ __launch_bounds__(512, 4) void attn_kernel(
    const __hip_bfloat16* __restrict__ Qs,  // [B,H,S,Hd], pre-scaled
    const __hip_bfloat16* __restrict__ Kb,  // [B,H,S,Hd]
    const __hip_bfloat16* __restrict__ Vt,  // [B,H,Hd,S]
    float* __restrict__ Opart,              // [512 wg][2 ph][128][64] f32
    float* __restrict__ MLpart)             // [512 wg][2 ph][128][2] f32
{
    __shared__ __align__(16) __hip_bfloat16 Kt[3][64 * 64];
    __shared__ __align__(16) __hip_bfloat16 Vs[3][64 * 64];
    __shared__ __align__(16) __hip_bfloat16 Pall[8][16 * P_PITCH];

    const int tid  = threadIdx.x;
    const int lane = tid & 63;
    const int wv   = tid >> 6;              // 0..7
    const int p    = blockIdx.x >> 1;       // pair index 0..7
    const int kh   = blockIdx.x & 1;        // key-range half 0/1
    const int bh   = blockIdx.y;
    const int wgid = bh * 16 + blockIdx.x;

    const int lm  = lane & 15;
    const int q4  = lane >> 4;
    const int lk  = q4 * 8;
    const int swz = (lm & 3) << 4;

    __hip_bfloat16* P = Pall[wv];

    const __hip_bfloat16* Qbh = Qs + (size_t)bh * SEQ * HDIM;
    const __hip_bfloat16* Kbh = Kb + (size_t)bh * SEQ * HDIM;
    const __hip_bfloat16* Vbh = Vt + (size_t)bh * HDIM * SEQ;

    // staging address components: 512 threads, 8 threads x 16B per 128B row
    const int srow = tid >> 3;              // 0..63 (k-row for Kt, d-row for Vs)
    const int scb  = (tid & 7) ^ (srow & 7);   // XOR-swizzled column block

    for (int ph = 0; ph < 2; ++ph) {
        const int qb    = ph ? p : 15 - p;     // heavy first, then light
        const int wbase = qb * 128 + wv * 16;  // this wave's 16 q-rows
        const int nCh   = qb + 1;              // chunks this WG handles
        const int c0    = kh * nCh;            // first global chunk index

        short8 qa[2];
#pragma unroll
        for (int h = 0; h < 2; ++h)
            qa[h] = load8(&Qbh[(size_t)(wbase + lm) * HDIM + h * 32 + lk]);

        float m_run = NEG_SENT;
        float l_run = 0.f;
        f32x4 Oacc[4];
#pragma unroll
        for (int t = 0; t < 4; ++t) Oacc[t] = (f32x4){0.f, 0.f, 0.f, 0.f};

        // protect ring buffers from the previous phase's in-flight compute
        __builtin_amdgcn_s_barrier();

        // prologue: stage first (up to) two chunks into slots 0,1
        {
            const int kk0 = c0 * 64;
            async16(&Kbh[(size_t)(kk0 + srow) * HDIM + scb * 8], (char*)Kt[0] + tid * 16);
            async16(&Vbh[(size_t)srow * SEQ + kk0 + scb * 8],    (char*)Vs[0] + tid * 16);
            if (nCh >= 2) {
                const int kk1 = kk0 + 64;
                async16(&Kbh[(size_t)(kk1 + srow) * HDIM + scb * 8], (char*)Kt[1] + tid * 16);
                async16(&Vbh[(size_t)srow * SEQ + kk1 + scb * 8],    (char*)Vs[1] + tid * 16);
            }
        }

        int cur = 0;
        for (int ci = 0; ci < nCh; ++ci) {
            const int k0 = (c0 + ci) * 64;

            if (ci + 1 < nCh) {
                // wait until only chunk ci+1's 2 loads remain -> ci's done
                asm volatile("s_waitcnt vmcnt(2)" ::: "memory");
            } else {
                asm volatile("s_waitcnt vmcnt(0)" ::: "memory");
            }
            __builtin_amdgcn_s_barrier();          // everyone done with buf[(ci+2)%3]
            __builtin_amdgcn_sched_barrier(0);

            if (ci + 2 < nCh) {                    // stage chunk ci+2 (overlaps compute)
                const int slot = (cur + 2 >= 3) ? cur - 1 : cur + 2;
                const int kk = (c0 + ci + 2) * 64;
                async16(&Kbh[(size_t)(kk + srow) * HDIM + scb * 8], (char*)Kt[slot] + tid * 16);
                async16(&Vbh[(size_t)srow * SEQ + kk + scb * 8],    (char*)Vs[slot] + tid * 16);
            }

            if (k0 <= wbase + 15) {   // not fully masked for this wave
                const __hip_bfloat16* Kc = Kt[cur];
                const __hip_bfloat16* Vc = Vs[cur];

                short8 ka[4][2];
#pragma unroll
                for (int t = 0; t < 4; ++t)
#pragma unroll
                    for (int h = 0; h < 2; ++h)
                        ka[t][h] = *(const short8*)&Kc[(t * 16 + lm) * 64 +
                                                       (((h * 4 + q4) ^ (lm & 7)) * 8)];

                f32x4 sc[4];
#pragma unroll
                for (int t = 0; t < 4; ++t) sc[t] = (f32x4){0.f, 0.f, 0.f, 0.f};
                __builtin_amdgcn_s_setprio(1);
#pragma unroll
                for (int t = 0; t < 4; ++t) {
                    sc[t] = MFMA_BF16(ka[t][0], qa[0], sc[t]);
                    sc[t] = MFMA_BF16(ka[t][1], qa[1], sc[t]);
                }
                __builtin_amdgcn_s_setprio(0);

                if (k0 + 63 > wbase) {
                    const int row = wbase + lm;
#pragma unroll
                    for (int t = 0; t < 4; ++t)
#pragma unroll
                        for (int r = 0; r < 4; ++r) {
                            const int key = k0 + t * 16 + q4 * 4 + r;
                            if (key > row) sc[t][r] = NEG_SENT;
                        }
                }

                // online softmax (scores for q-row lm live in this lane)
                float mx = sc[0][0];
#pragma unroll
                for (int t = 0; t < 4; ++t)
#pragma unroll
                    for (int r = 0; r < 4; ++r) mx = fmaxf(mx, sc[t][r]);
                mx = fmaxf(mx, __shfl_xor(mx, 16));
                mx = fmaxf(mx, __shfl_xor(mx, 32));

                // defer-max (T13): only rescale when max grew by > 8 (log2)
                if (!__all(mx <= m_run + 8.0f)) {
                    const float mn = fmaxf(m_run, mx);
                    const float alpha = exp2f(m_run - mn);
                    m_run = mn;
                    l_run *= alpha;
#pragma unroll
                    for (int r = 0; r < 4; ++r) {
                        const float av = __shfl(alpha, q4 * 4 + r);
#pragma unroll
                        for (int t = 0; t < 4; ++t) Oacc[t][r] *= av;
                    }
                }

                float s = 0.f;
#pragma unroll
                for (int t = 0; t < 4; ++t)
#pragma unroll
                    for (int r = 0; r < 4; ++r) {
                        const float pv = exp2f(sc[t][r] - m_run);
                        sc[t][r] = pv;
                        s += pv;
                    }
                s += __shfl_xor(s, 16);
                s += __shfl_xor(s, 32);
                l_run += s;

#pragma unroll
                for (int t = 0; t < 4; ++t) {
                    short4v pk;
#pragma unroll
                    for (int r = 0; r < 4; ++r)
                        pk[r] = (short)__bfloat16_as_ushort(__float2bfloat16(sc[t][r]));
                    const int col = (t * 16 + q4 * 4) ^ swz;
                    *(short4v*)&P[lm * P_PITCH + col] = pk;
                }

                __builtin_amdgcn_s_setprio(1);
#pragma unroll
                for (int h = 0; h < 2; ++h) {
                    const short8 pa = *(const short8*)&P[lm * P_PITCH + ((h * 32 + lk) ^ swz)];
#pragma unroll
                    for (int t = 0; t < 4; ++t) {
                        const short8 vb = *(const short8*)&Vc[(t * 16 + lm) * 64 +
                                                              (((h * 4 + q4) ^ (lm & 7)) * 8)];
                        Oacc[t] = MFMA_BF16(pa, vb, Oacc[t]);
                    }
                }
                __builtin_amdgcn_s_setprio(0);
            }

            cur = (cur + 1 == 3) ? 0 : cur + 1;
        }

        // --- epilogue: store f32 partials for this phase's 16 rows/wave ---
        const size_t pbase = ((size_t)wgid * 2 + ph) * 128;
#pragma unroll
        for (int t = 0; t < 4; ++t)
#pragma unroll
            for (int r = 0; r < 4; ++r)
                Opart[(pbase + wv * 16 + q4 * 4 + r) * 64 + t * 16 + lm] = Oacc[t][r];
        if (lane < 16) {
            MLpart[(pbase + wv * 16 + lane) * 2 + 0] = m_run;
            MLpart[(pbase + wv * 16 + lane) * 2 + 1] = l_run;
        }
    }
}

// ---------------------------------------------------------------------------
// Kernel 2b: merge the two key-half partials per row, normalize, write bf16.
// One thread per (row, 16-d group): 32bh * 2048s * 4 = 262144 threads.
// ---------------------------------------------------------------------------
__global__ __launch_bounds__(256) void attn_merge_kernel(
    const float* __restrict__ Opart, const float* __restrict__ MLpart,
    __hip_bfloat16* __restrict__ O)
{
    const int idx  = blockIdx.x * 256 + threadIdx.x;
    const int d16  = idx & 3;
    const int grow = idx >> 2;             // bh*2048 + s
    const int bh   = grow >> 11;
    const int s    = grow & 2047;
    const int qb   = s >> 7;
    const int rin  = s & 127;
    const int p    = (qb >= 8) ? (15 - qb) : qb;
    const int ph   = (qb >= 8) ? 0 : 1;
    const size_t r0 = ((size_t)(bh * 16 + p * 2 + 0) * 2 + ph) * 128 + rin;
    const size_t r1 = ((size_t)(bh * 16 + p * 2 + 1) * 2 + ph) * 128 + rin;

    const float m1 = MLpart[r0 * 2], l1 = MLpart[r0 * 2 + 1];
    const float m2 = MLpart[r1 * 2], l2 = MLpart[r1 * 2 + 1];
    const float mm = fmaxf(m1, m2);
    const float a1 = exp2f(m1 - mm), a2 = exp2f(m2 - mm);
    const float inv = 1.0f / (a1 * l1 + a2 * l2);

    const f32x4* O1 = (const f32x4*)&Opart[r0 * 64 + d16 * 16];
    const f32x4* O2 = (const f32x4*)&Opart[r1 * 64 + d16 * 16];

    short8 out[2];
#pragma unroll
    for (int v = 0; v < 4; ++v) {
        const f32x4 x1 = O1[v], x2 = O2[v];
#pragma unroll
        for (int j = 0; j < 4; ++j)
            out[v >> 1][(v & 1) * 4 + j] = (short)__bfloat16_as_ushort(
                __float2bfloat16((a1 * x1[j] + a2 * x2[j]) * inv));
    }
    const int b = bh >> 4, hh = bh & 15;
    __hip_bfloat16* dst = &O[((size_t)b * SEQ + s) * DMODEL + hh * 64 + d16 * 16];
    ((short8*)dst)[0] = out[0];
    ((short8*)dst)[1] = out[1];
}

// ---------------------------------------------------------------------------
// Kernel 3: out projection, 128x64 tiles (512 WGs = 2 WGs/CU), double-
// buffered staging + T2 swizzle (same as qkv).
// ---------------------------------------------------------------------------
__global__ __launch_bounds__(256) void proj_gemm_kernel(
    const __hip_bfloat16* __restrict__ A,
    const __hip_bfloat16* __restrict__ W,
    const __hip_bfloat16* __restrict__ bias,
    void* __restrict__ outv,
    const int* __restrict__ flag)
{
    constexpr int Kd = DMODEL;
    __shared__ __align__(16) __hip_bfloat16 As[2][128 * 32];
    __shared__ __align__(16) __hip_bfloat16 Bs[2][64 * 32];

    const int tid   = threadIdx.x;
    const int lane  = tid & 63;
    const int w     = tid >> 6;
    const int mTile = blockIdx.y * 128;
    const int nTile = blockIdx.x * 64;
    const int wm    = (w >> 1) * 64;
    const int wn    = (w & 1) * 32;
    const int lm    = lane & 15;
    const int q4    = lane >> 4;
    const int lks   = (q4 ^ ((lm >> 1) & 3)) * 8;
    const bool f32out = (*flag != 0);

    f32x4 acc[4][2];
#pragma unroll
    for (int i = 0; i < 4; ++i)
#pragma unroll
        for (int j = 0; j < 2; ++j)
            acc[i][j] = (f32x4){0.f, 0.f, 0.f, 0.f};

    const int r0c = tid >> 2;
    const int r1c = (tid + 256) >> 2;
    const int cbs = ((tid & 3) ^ ((tid >> 3) & 3)) * 8;

    const __hip_bfloat16* gA0 = &A[(size_t)(mTile + r0c) * Kd + cbs];
    const __hip_bfloat16* gA1 = &A[(size_t)(mTile + r1c) * Kd + cbs];
    const __hip_bfloat16* gB0 = &W[(size_t)(nTile + r0c) * Kd + cbs];

    async16(gA0, (char*)As[0] + tid * 16);
    async16(gA1, (char*)As[0] + tid * 16 + 4096);
    async16(gB0, (char*)Bs[0] + tid * 16);

    int cur = 0;
    constexpr int NIT = Kd / 32;
    for (int it = 0; it < NIT; ++it) {
        if (it + 1 < NIT) {
            const int k1 = (it + 1) * 32;
            async16(gA0 + k1, (char*)As[cur ^ 1] + tid * 16);
            async16(gA1 + k1, (char*)As[cur ^ 1] + tid * 16 + 4096);
            async16(gB0 + k1, (char*)Bs[cur ^ 1] + tid * 16);
            asm volatile("s_waitcnt vmcnt(3)" ::: "memory");
        } else {
            asm volatile("s_waitcnt vmcnt(0)" ::: "memory");
        }
        __builtin_amdgcn_s_barrier();
        __builtin_amdgcn_sched_barrier(0);

        const __hip_bfloat16* Ac = As[cur];
        const __hip_bfloat16* Bc = Bs[cur];
        short8 a[4], b[2];
#pragma unroll
        for (int i = 0; i < 4; ++i)
            a[i] = *(const short8*)&Ac[(wm + i * 16 + lm) * 32 + lks];
#pragma unroll
        for (int j = 0; j < 2; ++j)
            b[j] = *(const short8*)&Bc[(wn + j * 16 + lm) * 32 + lks];
#pragma unroll
        for (int i = 0; i < 4; ++i)
#pragma unroll
            for (int j = 0; j < 2; ++j)
                acc[i][j] = MFMA_BF16(a[i], b[j], acc[i][j]);

        __builtin_amdgcn_s_barrier();
        cur ^= 1;
    }

    const int r0 = (lane >> 4) * 4;
#pragma unroll
    for (int j = 0; j < 2; ++j) {
        const int n = nTile + wn + j * 16 + lm;
        const float bv = __bfloat162float(bias[n]);
#pragma unroll
        for (int i = 0; i < 4; ++i) {
#pragma unroll
            for (int r = 0; r < 4; ++r) {
                const size_t m = mTile + wm + i * 16 + r0 + r;
                const float v = acc[i][j][r] + bv;
                if (f32out) ((float*)outv)[m * DMODEL + n] = v;
                else ((__hip_bfloat16*)outv)[m * DMODEL + n] = __float2bfloat16(v);
            }
        }
    }
}

// ---------------------------------------------------------------------------
extern "C" void kernel_launch(void* const* d_in, const int* in_sizes, int n_in,
                              void* d_out, int out_size, void* d_ws, size_t ws_size,
                              hipStream_t stream) {
    // Workspace layout (bytes):
    // [flag:256][canon bf16][Qs][Kb][Vt][Ao][Opart f32][MLpart f32]
    const size_t OFF_CANON = 256;
    const size_t OFF_QS = OFF_CANON + (size_t)N_CANON * 2;
    const size_t OFF_KB = OFF_QS + (size_t)NTOK * DMODEL * 2;
    const size_t OFF_VT = OFF_KB + (size_t)NTOK * DMODEL * 2;
    const size_t OFF_AO = OFF_VT + (size_t)NTOK * DMODEL * 2;
    const size_t OFF_OP = OFF_AO + (size_t)NTOK * DMODEL * 2;
    const size_t OFF_ML = OFF_OP + (size_t)512 * 2 * 128 * 64 * 4;   // 33.55 MB

    char* wsb = (char*)d_ws;
    int* flag = (int*)wsb;
    __hip_bfloat16* canon = (__hip_bfloat16*)(wsb + OFF_CANON);
    __hip_bfloat16* Xc = canon;
    __hip_bfloat16* Wq = Xc + N_X;
    __hip_bfloat16* Bq = Wq + N_WQ;
    __hip_bfloat16* Wo = Bq + N_BQ;
    __hip_bfloat16* Bo = Wo + N_WO;
    __hip_bfloat16* Qs = (__hip_bfloat16*)(wsb + OFF_QS);
    __hip_bfloat16* Kb = (__hip_bfloat16*)(wsb + OFF_KB);
    __hip_bfloat16* Vt = (__hip_bfloat16*)(wsb + OFF_VT);
    __hip_bfloat16* Ao = (__hip_bfloat16*)(wsb + OFF_AO);
    float* Opart = (float*)(wsb + OFF_OP);
    float* MLpart = (float*)(wsb + OFF_ML);

    // 0) dtype detect + canonicalize (vectorized, 8 elems/thread)
    detect_kernel<<<1, 64, 0, stream>>>((const unsigned short*)d_in[1], flag);
    canon_kernel<<<(N_CANON / 8 + 255) / 256, 256, 0, stream>>>(
        d_in[0], d_in[1], d_in[2], d_in[3], d_in[4], canon, flag);

    // 1) QKV GEMM
    {
        dim3 grid(3 * DMODEL / 128, NTOK / 128);
        qkv_gemm_kernel<<<grid, 256, 0, stream>>>(Xc, Wq, Bq, Qs, Kb, Vt);
    }
    // 2) Attention: split-K pair-balanced, grid (16, B*H) = 512 WGs of 8
    //    waves; every WG exactly 17 chunks; 2 WGs/CU -> 4 waves/SIMD.
    {
        dim3 grid(16, BATCH * NHEAD);
        attn_kernel<<<grid, 512, 0, stream>>>(Qs, Kb, Vt, Opart, MLpart);
        attn_merge_kernel<<<(NTOK * NHEAD * 4) / 256, 256, 0, stream>>>(
            Opart, MLpart, Ao);
    }
    // 3) Out projection: 128x64 tiles -> 512 WGs (2 WGs/CU)
    {
        dim3 grid(DMODEL / 64, NTOK / 128);
        proj_gemm_kernel<<<grid, 256, 0, stream>>>(Ao, Wo, Bo, d_out, flag);
    }
}

// Round 6
// 190.625 us; speedup vs baseline: 1.2193x; 1.0081x over previous
//
#include <hip/hip_runtime.h>
#include <hip/hip_bf16.h>

// Sizes (fixed): B=2, S=2048, D=1024, H=16, Hd=64
#define SEQ    2048
#define DMODEL 1024
#define NHEAD  16
#define HDIM   64
#define BATCH  2
#define NTOK   (BATCH * SEQ)           // 4096

#define N_X   (NTOK * DMODEL)
#define N_WQ  (3 * DMODEL * DMODEL)
#define N_BQ  (3 * DMODEL)
#define N_WO  (DMODEL * DMODEL)
#define N_BO  (DMODEL)
#define N_CANON (N_X + N_WQ + N_BQ + N_WO + N_BO)   // 8,392,704

#define NEG_SENT (-1.0e30f)
#define QSCALE 0.1803368801111f        // (1/8) * log2(e)

typedef __attribute__((ext_vector_type(8))) short short8;
typedef __attribute__((ext_vector_type(4))) short short4v;
typedef __attribute__((ext_vector_type(4))) float f32x4;

#define MFMA_BF16(A, B, C) __builtin_amdgcn_mfma_f32_16x16x32_bf16((A), (B), (C), 0, 0, 0)

static __device__ __forceinline__ short8 load8(const __hip_bfloat16* p) {
    return *(const short8*)p;
}

static __device__ __forceinline__ void async16(const void* g, void* l) {
    __builtin_amdgcn_global_load_lds(
        (const __attribute__((address_space(1))) unsigned int*)g,
        (__attribute__((address_space(3))) unsigned int*)l,
        16, 0, 0);
}

// ---------------------------------------------------------------------------
// Kernel 0: dtype detector (confirmed fp32 in round 2; keep for robustness)
// ---------------------------------------------------------------------------
__global__ void detect_kernel(const unsigned short* __restrict__ w, int* flag) {
    int cnt = 0;
    for (int i = threadIdx.x; i < 512; i += 64) {
        const unsigned e = (w[i] >> 7) & 0xFF;
        if (e >= 125) cnt++;
    }
#pragma unroll
    for (int o = 32; o; o >>= 1) cnt += __shfl_down(cnt, o);
    if (threadIdx.x == 0) *flag = (cnt > 8) ? 1 : 0;
}

// ---------------------------------------------------------------------------
// Kernel 0b: canonicalize inputs to bf16, vectorized 8 elems/thread.
// ---------------------------------------------------------------------------
__global__ __launch_bounds__(256) void canon_kernel(
    const void* __restrict__ s0, const void* __restrict__ s1,
    const void* __restrict__ s2, const void* __restrict__ s3,
    const void* __restrict__ s4,
    __hip_bfloat16* __restrict__ dst, const int* __restrict__ flag)
{
    const int v = blockIdx.x * 256 + threadIdx.x;
    if (v >= N_CANON / 8) return;
    const int idx = v * 8;
    const void* src;
    int off;
    if (idx < N_X)                          { src = s0; off = idx; }
    else if (idx < N_X + N_WQ)              { src = s1; off = idx - N_X; }
    else if (idx < N_X + N_WQ + N_BQ)       { src = s2; off = idx - (N_X + N_WQ); }
    else if (idx < N_X + N_WQ + N_BQ + N_WO){ src = s3; off = idx - (N_X + N_WQ + N_BQ); }
    else                                    { src = s4; off = idx - (N_X + N_WQ + N_BQ + N_WO); }
    if (*flag != 0) {
        const f32x4* sp = (const f32x4*)((const float*)src + off);
        const f32x4 x0 = sp[0], x1 = sp[1];
        short8 o;
#pragma unroll
        for (int j = 0; j < 4; ++j) {
            o[j]     = (short)__bfloat16_as_ushort(__float2bfloat16(x0[j]));
            o[4 + j] = (short)__bfloat16_as_ushort(__float2bfloat16(x1[j]));
        }
        *(short8*)&dst[idx] = o;
    } else {
        *(short8*)&dst[idx] = *(const short8*)((const __hip_bfloat16*)src + off);
    }
}

// ---------------------------------------------------------------------------
// Kernel 1: QKV GEMM, m97 structure + dbuf (counted vmcnt) + T2 swizzle.
// (unchanged from round 14)
// ---------------------------------------------------------------------------
__global__ __launch_bounds__(256) void qkv_gemm_kernel(
    const __hip_bfloat16* __restrict__ X,
    const __hip_bfloat16* __restrict__ W,
    const __hip_bfloat16* __restrict__ bias,
    __hip_bfloat16* __restrict__ Qs,
    __hip_bfloat16* __restrict__ Kb,
    __hip_bfloat16* __restrict__ Vt)
{
    constexpr int Kd = DMODEL;
    __shared__ __align__(16) __hip_bfloat16 As[2][128 * 32];
    __shared__ __align__(16) __hip_bfloat16 Bs[2][128 * 32];

    const int tid   = threadIdx.x;
    const int lane  = tid & 63;
    const int w     = tid >> 6;
    const int mTile = blockIdx.y * 128;
    const int nTile = blockIdx.x * 128;
    const int wm    = (w >> 1) * 64;
    const int wn    = (w & 1) * 64;
    const int lm    = lane & 15;
    const int q4    = lane >> 4;
    const int lks   = (q4 ^ ((lm >> 1) & 3)) * 8;

    f32x4 acc[4][4];
#pragma unroll
    for (int i = 0; i < 4; ++i)
#pragma unroll
        for (int j = 0; j < 4; ++j)
            acc[i][j] = (f32x4){0.f, 0.f, 0.f, 0.f};

    const int r0c = tid >> 2;
    const int r1c = (tid + 256) >> 2;
    const int cbs = ((tid & 3) ^ ((tid >> 3) & 3)) * 8;

    const __hip_bfloat16* gA0 = &X[(size_t)(mTile + r0c) * Kd + cbs];
    const __hip_bfloat16* gA1 = &X[(size_t)(mTile + r1c) * Kd + cbs];
    const __hip_bfloat16* gB0 = &W[(size_t)(nTile + r0c) * Kd + cbs];
    const __hip_bfloat16* gB1 = &W[(size_t)(nTile + r1c) * Kd + cbs];

    async16(gA0, (char*)As[0] + tid * 16);
    async16(gA1, (char*)As[0] + tid * 16 + 4096);
    async16(gB0, (char*)Bs[0] + tid * 16);
    async16(gB1, (char*)Bs[0] + tid * 16 + 4096);

    int cur = 0;
    constexpr int NIT = Kd / 32;
    for (int it = 0; it < NIT; ++it) {
        if (it + 1 < NIT) {
            const int k1 = (it + 1) * 32;
            async16(gA0 + k1, (char*)As[cur ^ 1] + tid * 16);
            async16(gA1 + k1, (char*)As[cur ^ 1] + tid * 16 + 4096);
            async16(gB0 + k1, (char*)Bs[cur ^ 1] + tid * 16);
            async16(gB1 + k1, (char*)Bs[cur ^ 1] + tid * 16 + 4096);
            asm volatile("s_waitcnt vmcnt(4)" ::: "memory");
        } else {
            asm volatile("s_waitcnt vmcnt(0)" ::: "memory");
        }
        __builtin_amdgcn_s_barrier();
        __builtin_amdgcn_sched_barrier(0);

        const __hip_bfloat16* Ac = As[cur];
        const __hip_bfloat16* Bc = Bs[cur];
        short8 a[4], b[4];
#pragma unroll
        for (int i = 0; i < 4; ++i)
            a[i] = *(const short8*)&Ac[(wm + i * 16 + lm) * 32 + lks];
#pragma unroll
        for (int j = 0; j < 4; ++j)
            b[j] = *(const short8*)&Bc[(wn + j * 16 + lm) * 32 + lks];
#pragma unroll
        for (int i = 0; i < 4; ++i)
#pragma unroll
            for (int j = 0; j < 4; ++j)
                acc[i][j] = MFMA_BF16(a[i], b[j], acc[i][j]);

        __builtin_amdgcn_s_barrier();
        cur ^= 1;
    }

    const int r0 = (lane >> 4) * 4;
#pragma unroll
    for (int j = 0; j < 4; ++j) {
        const int n  = nTile + wn + j * 16 + lm;
        const float bv = __bfloat162float(bias[n]);
        const int c = n >> 10;
        const int h = (n >> 6) & 15;
        const int d = n & 63;
#pragma unroll
        for (int i = 0; i < 4; ++i) {
            if (c == 2) {
                const int m0 = mTile + wm + i * 16 + r0;
                const int bb = m0 >> 11;
                const int s0 = m0 & (SEQ - 1);
                const int bh = bb * NHEAD + h;
                short4v pk;
#pragma unroll
                for (int r = 0; r < 4; ++r)
                    pk[r] = (short)__bfloat16_as_ushort(
                        __float2bfloat16(acc[i][j][r] + bv));
                *(short4v*)&Vt[(size_t)(bh * HDIM + d) * SEQ + s0] = pk;
            } else {
#pragma unroll
                for (int r = 0; r < 4; ++r) {
                    const int m  = mTile + wm + i * 16 + r0 + r;
                    const int bb = m >> 11;
                    const int s  = m & (SEQ - 1);
                    const int bh = bb * NHEAD + h;
                    const float v = acc[i][j][r] + bv;
                    if (c == 0) {
                        Qs[(size_t)(bh * SEQ + s) * HDIM + d] = __float2bfloat16(v * QSCALE);
                    } else {
                        Kb[(size_t)(bh * SEQ + s) * HDIM + d] = __float2bfloat16(v);
                    }
                }
            }
        }
    }
}

// ---------------------------------------------------------------------------
// Kernel 2: cooperative causal flash attention, 3-WAY SPLIT-K pair-balanced.
//
// Round-15 changes vs round 14 (50.4 us, Occ 33%, VALUBusy 48%):
//  - setprio REVERTED (regressed 47.8->50.4; m190: null/negative for
//    barrier-locked lockstep structures).
//  - 3-way split-K: pair (heavy qb=15-p, light qb=p) = 34 chunks split
//    [0,12)[12,23)[23,34) across 3 WGs -> grid (32 bh, 24) = 768 WGs =
//    3 WGs/CU (LDS 51.2KB, 3x fits 160KB) = 6 waves/SIMD (was 4).
//    A WG's range may span the heavy/light boundary -> <=2 segments,
//    each with own (m,l,O) partial; <=3 contributors per (pair,block),
//    packed into 5 slots/pair.  2-stage dbuf, 2 barriers/chunk.
//  - XCD clustering: blockIdx.x = bh -> linear%8 = bh%8 -> all 24 WGs of
//    a head on one XCD; its 1MB K/V fits that XCD's 4MB L2 (T1).
// ---------------------------------------------------------------------------
#define P_PITCH 72
__global__ __launch_bounds__(512, 6) void attn_kernel(
    const __hip_bfloat16* __restrict__ Qs,  // [B,H,S,Hd], pre-scaled
    const __hip_bfloat16* __restrict__ Kb,  // [B,H,S,Hd]
    const __hip_bfloat16* __restrict__ Vt,  // [B,H,Hd,S]
    float* __restrict__ Opart,              // [32 bh][8 p][5 slot][128][64] f32
    float* __restrict__ MLpart)             // [32 bh][8 p][5 slot][128][2] f32
{
    __shared__ __align__(16) __hip_bfloat16 Kt[2][64 * 64];
    __shared__ __align__(16) __hip_bfloat16 Vs[2][64 * 64];
    __shared__ __align__(16) __hip_bfloat16 Pall[8][16 * P_PITCH];

    const int tid  = threadIdx.x;
    const int lane = tid & 63;
    const int wv   = tid >> 6;              // 0..7
    const int bh   = blockIdx.x;            // XCD = bh % 8
    const int py   = blockIdx.y;            // 0..23
    const int p    = py / 3;                // pair index 0..7
    const int j3   = py % 3;                // third index 0..2

    // concatenated chunk range for this WG: [c_lo, c_hi) of the pair's 34
    const int c_lo = (j3 == 0) ? 0 : (j3 == 1 ? 12 : 23);
    const int c_hi = (j3 == 0) ? 12 : (j3 == 1 ? 23 : 34);
    const int bnd  = 32 - 2 * p;            // heavy block's chunk count

    const int lm  = lane & 15;
    const int q4  = lane >> 4;
    const int lk  = q4 * 8;
    const int swz = (lm & 3) << 4;

    __hip_bfloat16* P = Pall[wv];

    const __hip_bfloat16* Qbh = Qs + (size_t)bh * SEQ * HDIM;
    const __hip_bfloat16* Kbh = Kb + (size_t)bh * SEQ * HDIM;
    const __hip_bfloat16* Vbh = Vt + (size_t)bh * HDIM * SEQ;

    const int srow = tid >> 3;              // 0..63
    const int scb  = (tid & 7) ^ (srow & 7);

    for (int seg = 0; seg < 2; ++seg) {
        int qb, a, b, slot;
        if (seg == 0) {                      // heavy block qb = 15-p
            if (j3 == 2 && p >= 5) continue; // empty
            qb = 15 - p; a = c_lo;
            b  = (c_hi < bnd) ? c_hi : bnd;
            slot = j3;                       // 0,1,2
        } else {                             // light block qb = p
            if (j3 == 0 || (j3 == 1 && p <= 4)) continue; // empty
            qb = p;
            a  = ((c_lo > bnd) ? c_lo : bnd) - bnd;
            b  = c_hi - bnd;
            slot = (j3 == 2) ? 3 : 4;
        }

        const int wbase = qb * 128 + wv * 16;

        short8 qa[2];
#pragma unroll
        for (int h = 0; h < 2; ++h)
            qa[h] = load8(&Qbh[(size_t)(wbase + lm) * HDIM + h * 32 + lk]);

        float m_run = NEG_SENT;
        float l_run = 0.f;
        f32x4 Oacc[4];
#pragma unroll
        for (int t = 0; t < 4; ++t) Oacc[t] = (f32x4){0.f, 0.f, 0.f, 0.f};

        // protect ring buffers from the previous segment's in-flight reads
        __builtin_amdgcn_s_barrier();

        // prologue: stage chunks a, a+1 into slots 0,1
        {
            const int kk0 = a * 64;
            async16(&Kbh[(size_t)(kk0 + srow) * HDIM + scb * 8], (char*)Kt[0] + tid * 16);
            async16(&Vbh[(size_t)srow * SEQ + kk0 + scb * 8],    (char*)Vs[0] + tid * 16);
            if (a + 1 < b) {
                const int kk1 = kk0 + 64;
                async16(&Kbh[(size_t)(kk1 + srow) * HDIM + scb * 8], (char*)Kt[1] + tid * 16);
                async16(&Vbh[(size_t)srow * SEQ + kk1 + scb * 8],    (char*)Vs[1] + tid * 16);
            }
        }

        int cur = 0;
        for (int ci = a; ci < b; ++ci) {
            const int k0 = ci * 64;

            if (ci + 1 < b) {
                asm volatile("s_waitcnt vmcnt(2)" ::: "memory");
            } else {
                asm volatile("s_waitcnt vmcnt(0)" ::: "memory");
            }
            __builtin_amdgcn_s_barrier();          // chunk ci visible
            __builtin_amdgcn_sched_barrier(0);

            if (k0 <= wbase + 15) {   // not fully masked for this wave
                const __hip_bfloat16* Kc = Kt[cur];
                const __hip_bfloat16* Vc = Vs[cur];

                short8 ka[4][2];
#pragma unroll
                for (int t = 0; t < 4; ++t)
#pragma unroll
                    for (int h = 0; h < 2; ++h)
                        ka[t][h] = *(const short8*)&Kc[(t * 16 + lm) * 64 +
                                                       (((h * 4 + q4) ^ (lm & 7)) * 8)];

                f32x4 sc[4];
#pragma unroll
                for (int t = 0; t < 4; ++t) sc[t] = (f32x4){0.f, 0.f, 0.f, 0.f};
#pragma unroll
                for (int t = 0; t < 4; ++t) {
                    sc[t] = MFMA_BF16(ka[t][0], qa[0], sc[t]);
                    sc[t] = MFMA_BF16(ka[t][1], qa[1], sc[t]);
                }

                if (k0 + 63 > wbase) {
                    const int row = wbase + lm;
#pragma unroll
                    for (int t = 0; t < 4; ++t)
#pragma unroll
                        for (int r = 0; r < 4; ++r) {
                            const int key = k0 + t * 16 + q4 * 4 + r;
                            if (key > row) sc[t][r] = NEG_SENT;
                        }
                }

                float mx = sc[0][0];
#pragma unroll
                for (int t = 0; t < 4; ++t)
#pragma unroll
                    for (int r = 0; r < 4; ++r) mx = fmaxf(mx, sc[t][r]);
                mx = fmaxf(mx, __shfl_xor(mx, 16));
                mx = fmaxf(mx, __shfl_xor(mx, 32));

                // defer-max (T13)
                if (!__all(mx <= m_run + 8.0f)) {
                    const float mn = fmaxf(m_run, mx);
                    const float alpha = exp2f(m_run - mn);
                    m_run = mn;
                    l_run *= alpha;
#pragma unroll
                    for (int r = 0; r < 4; ++r) {
                        const float av = __shfl(alpha, q4 * 4 + r);
#pragma unroll
                        for (int t = 0; t < 4; ++t) Oacc[t][r] *= av;
                    }
                }

                float s = 0.f;
#pragma unroll
                for (int t = 0; t < 4; ++t)
#pragma unroll
                    for (int r = 0; r < 4; ++r) {
                        const float pv = exp2f(sc[t][r] - m_run);
                        sc[t][r] = pv;
                        s += pv;
                    }
                s += __shfl_xor(s, 16);
                s += __shfl_xor(s, 32);
                l_run += s;

#pragma unroll
                for (int t = 0; t < 4; ++t) {
                    short4v pk;
#pragma unroll
                    for (int r = 0; r < 4; ++r)
                        pk[r] = (short)__bfloat16_as_ushort(__float2bfloat16(sc[t][r]));
                    const int col = (t * 16 + q4 * 4) ^ swz;
                    *(short4v*)&P[lm * P_PITCH + col] = pk;
                }

#pragma unroll
                for (int h = 0; h < 2; ++h) {
                    const short8 pa = *(const short8*)&P[lm * P_PITCH + ((h * 32 + lk) ^ swz)];
#pragma unroll
                    for (int t = 0; t < 4; ++t) {
                        const short8 vb = *(const short8*)&Vc[(t * 16 + lm) * 64 +
                                                              (((h * 4 + q4) ^ (lm & 7)) * 8)];
                        Oacc[t] = MFMA_BF16(pa, vb, Oacc[t]);
                    }
                }
            }

            __builtin_amdgcn_s_barrier();   // all waves done reading buf[cur]
            if (ci + 2 < b) {               // stage chunk ci+2 into freed buf
                const int kk = (ci + 2) * 64;
                async16(&Kbh[(size_t)(kk + srow) * HDIM + scb * 8], (char*)Kt[cur] + tid * 16);
                async16(&Vbh[(size_t)srow * SEQ + kk + scb * 8],    (char*)Vs[cur] + tid * 16);
            }
            cur ^= 1;
        }

        // --- epilogue: store f32 partials for this segment ---
        const size_t pbase = ((size_t)(bh * 8 + p) * 5 + slot) * 128;
#pragma unroll
        for (int t = 0; t < 4; ++t)
#pragma unroll
            for (int r = 0; r < 4; ++r)
                Opart[(pbase + wv * 16 + q4 * 4 + r) * 64 + t * 16 + lm] = Oacc[t][r];
        if (lane < 16) {
            MLpart[(pbase + wv * 16 + lane) * 2 + 0] = m_run;
            MLpart[(pbase + wv * 16 + lane) * 2 + 1] = l_run;
        }
    }
}

// ---------------------------------------------------------------------------
// Kernel 2b: merge up to 3 partials per row, normalize, write bf16.
// Heavy block (qb>=8, p=15-qb): slots {0,1} + {2 if p<=4}.
// Light block (qb<=7, p=qb):    slot  {3} + {4 if p>=5}.
// ---------------------------------------------------------------------------
__global__ __launch_bounds__(256) void attn_merge_kernel(
    const float* __restrict__ Opart, const float* __restrict__ MLpart,
    __hip_bfloat16* __restrict__ O)
{
    const int idx  = blockIdx.x * 256 + threadIdx.x;
    const int d16  = idx & 3;
    const int grow = idx >> 2;             // bh*2048 + s
    const int bh   = grow >> 11;
    const int s    = grow & 2047;
    const int qb   = s >> 7;
    const int rin  = s & 127;

    const bool heavy = (qb >= 8);
    const int p  = heavy ? (15 - qb) : qb;
    const int s0 = heavy ? 0 : 3;
    const int s1 = heavy ? 1 : 4;
    const bool v1 = heavy ? true : (p >= 5);
    const bool v2 = heavy && (p <= 4);     // slot 2

    const size_t rb = (size_t)(bh * 8 + p) * 5;
    const size_t r0 = (rb + s0) * 128 + rin;
    const size_t r1 = (rb + s1) * 128 + rin;
    const size_t r2 = (rb + 2)  * 128 + rin;

    const float m0 = MLpart[r0 * 2],                 l0 = MLpart[r0 * 2 + 1];
    const float m1 = v1 ? MLpart[r1 * 2] : NEG_SENT, l1 = v1 ? MLpart[r1 * 2 + 1] : 0.f;
    const float m2 = v2 ? MLpart[r2 * 2] : NEG_SENT, l2 = v2 ? MLpart[r2 * 2 + 1] : 0.f;

    float mm = fmaxf(m0, fmaxf(m1, m2));
    const float a0 = exp2f(m0 - mm);
    const float a1 = v1 ? exp2f(m1 - mm) : 0.f;
    const float a2 = v2 ? exp2f(m2 - mm) : 0.f;
    const float inv = 1.0f / (a0 * l0 + a1 * l1 + a2 * l2);

    f32x4 o[4];
    {
        const f32x4* O0 = (const f32x4*)&Opart[r0 * 64 + d16 * 16];
#pragma unroll
        for (int v = 0; v < 4; ++v) o[v] = a0 * O0[v];
    }
    if (v1) {
        const f32x4* O1 = (const f32x4*)&Opart[r1 * 64 + d16 * 16];
#pragma unroll
        for (int v = 0; v < 4; ++v) o[v] += a1 * O1[v];
    }
    if (v2) {
        const f32x4* O2 = (const f32x4*)&Opart[r2 * 64 + d16 * 16];
#pragma unroll
        for (int v = 0; v < 4; ++v) o[v] += a2 * O2[v];
    }

    short8 out[2];
#pragma unroll
    for (int v = 0; v < 4; ++v)
#pragma unroll
        for (int jj = 0; jj < 4; ++jj)
            out[v >> 1][(v & 1) * 4 + jj] = (short)__bfloat16_as_ushort(
                __float2bfloat16(o[v][jj] * inv));

    const int b = bh >> 4, hh = bh & 15;
    __hip_bfloat16* dst = &O[((size_t)b * SEQ + s) * DMODEL + hh * 64 + d16 * 16];
    ((short8*)dst)[0] = out[0];
    ((short8*)dst)[1] = out[1];
}

// ---------------------------------------------------------------------------
// Kernel 3: out projection, 128x64 tiles (512 WGs), dbuf + T2 swizzle.
// (unchanged from round 14)
// ---------------------------------------------------------------------------
__global__ __launch_bounds__(256) void proj_gemm_kernel(
    const __hip_bfloat16* __restrict__ A,
    const __hip_bfloat16* __restrict__ W,
    const __hip_bfloat16* __restrict__ bias,
    void* __restrict__ outv,
    const int* __restrict__ flag)
{
    constexpr int Kd = DMODEL;
    __shared__ __align__(16) __hip_bfloat16 As[2][128 * 32];
    __shared__ __align__(16) __hip_bfloat16 Bs[2][64 * 32];

    const int tid   = threadIdx.x;
    const int lane  = tid & 63;
    const int w     = tid >> 6;
    const int mTile = blockIdx.y * 128;
    const int nTile = blockIdx.x * 64;
    const int wm    = (w >> 1) * 64;
    const int wn    = (w & 1) * 32;
    const int lm    = lane & 15;
    const int q4    = lane >> 4;
    const int lks   = (q4 ^ ((lm >> 1) & 3)) * 8;
    const bool f32out = (*flag != 0);

    f32x4 acc[4][2];
#pragma unroll
    for (int i = 0; i < 4; ++i)
#pragma unroll
        for (int j = 0; j < 2; ++j)
            acc[i][j] = (f32x4){0.f, 0.f, 0.f, 0.f};

    const int r0c = tid >> 2;
    const int r1c = (tid + 256) >> 2;
    const int cbs = ((tid & 3) ^ ((tid >> 3) & 3)) * 8;

    const __hip_bfloat16* gA0 = &A[(size_t)(mTile + r0c) * Kd + cbs];
    const __hip_bfloat16* gA1 = &A[(size_t)(mTile + r1c) * Kd + cbs];
    const __hip_bfloat16* gB0 = &W[(size_t)(nTile + r0c) * Kd + cbs];

    async16(gA0, (char*)As[0] + tid * 16);
    async16(gA1, (char*)As[0] + tid * 16 + 4096);
    async16(gB0, (char*)Bs[0] + tid * 16);

    int cur = 0;
    constexpr int NIT = Kd / 32;
    for (int it = 0; it < NIT; ++it) {
        if (it + 1 < NIT) {
            const int k1 = (it + 1) * 32;
            async16(gA0 + k1, (char*)As[cur ^ 1] + tid * 16);
            async16(gA1 + k1, (char*)As[cur ^ 1] + tid * 16 + 4096);
            async16(gB0 + k1, (char*)Bs[cur ^ 1] + tid * 16);
            asm volatile("s_waitcnt vmcnt(3)" ::: "memory");
        } else {
            asm volatile("s_waitcnt vmcnt(0)" ::: "memory");
        }
        __builtin_amdgcn_s_barrier();
        __builtin_amdgcn_sched_barrier(0);

        const __hip_bfloat16* Ac = As[cur];
        const __hip_bfloat16* Bc = Bs[cur];
        short8 a[4], b[2];
#pragma unroll
        for (int i = 0; i < 4; ++i)
            a[i] = *(const short8*)&Ac[(wm + i * 16 + lm) * 32 + lks];
#pragma unroll
        for (int j = 0; j < 2; ++j)
            b[j] = *(const short8*)&Bc[(wn + j * 16 + lm) * 32 + lks];
#pragma unroll
        for (int i = 0; i < 4; ++i)
#pragma unroll
            for (int j = 0; j < 2; ++j)
                acc[i][j] = MFMA_BF16(a[i], b[j], acc[i][j]);

        __builtin_amdgcn_s_barrier();
        cur ^= 1;
    }

    const int r0 = (lane >> 4) * 4;
#pragma unroll
    for (int j = 0; j < 2; ++j) {
        const int n = nTile + wn + j * 16 + lm;
        const float bv = __bfloat162float(bias[n]);
#pragma unroll
        for (int i = 0; i < 4; ++i) {
#pragma unroll
            for (int r = 0; r < 4; ++r) {
                const size_t m = mTile + wm + i * 16 + r0 + r;
                const float v = acc[i][j][r] + bv;
                if (f32out) ((float*)outv)[m * DMODEL + n] = v;
                else ((__hip_bfloat16*)outv)[m * DMODEL + n] = __float2bfloat16(v);
            }
        }
    }
}

// ---------------------------------------------------------------------------
extern "C" void kernel_launch(void* const* d_in, const int* in_sizes, int n_in,
                              void* d_out, int out_size, void* d_ws, size_t ws_size,
                              hipStream_t stream) {
    // Workspace layout (bytes):
    // [flag:256][canon bf16][Qs][Kb][Vt][Ao][Opart f32][MLpart f32]
    const size_t OFF_CANON = 256;
    const size_t OFF_QS = OFF_CANON + (size_t)N_CANON * 2;
    const size_t OFF_KB = OFF_QS + (size_t)NTOK * DMODEL * 2;
    const size_t OFF_VT = OFF_KB + (size_t)NTOK * DMODEL * 2;
    const size_t OFF_AO = OFF_VT + (size_t)NTOK * DMODEL * 2;
    const size_t OFF_OP = OFF_AO + (size_t)NTOK * DMODEL * 2;
    const size_t OFF_ML = OFF_OP + (size_t)32 * 8 * 5 * 128 * 64 * 4;  // 41.94 MB

    char* wsb = (char*)d_ws;
    int* flag = (int*)wsb;
    __hip_bfloat16* canon = (__hip_bfloat16*)(wsb + OFF_CANON);
    __hip_bfloat16* Xc = canon;
    __hip_bfloat16* Wq = Xc + N_X;
    __hip_bfloat16* Bq = Wq + N_WQ;
    __hip_bfloat16* Wo = Bq + N_BQ;
    __hip_bfloat16* Bo = Wo + N_WO;
    __hip_bfloat16* Qs = (__hip_bfloat16*)(wsb + OFF_QS);
    __hip_bfloat16* Kb = (__hip_bfloat16*)(wsb + OFF_KB);
    __hip_bfloat16* Vt = (__hip_bfloat16*)(wsb + OFF_VT);
    __hip_bfloat16* Ao = (__hip_bfloat16*)(wsb + OFF_AO);
    float* Opart = (float*)(wsb + OFF_OP);
    float* MLpart = (float*)(wsb + OFF_ML);

    // 0) dtype detect + canonicalize (vectorized, 8 elems/thread)
    detect_kernel<<<1, 64, 0, stream>>>((const unsigned short*)d_in[1], flag);
    canon_kernel<<<(N_CANON / 8 + 255) / 256, 256, 0, stream>>>(
        d_in[0], d_in[1], d_in[2], d_in[3], d_in[4], canon, flag);

    // 1) QKV GEMM
    {
        dim3 grid(3 * DMODEL / 128, NTOK / 128);
        qkv_gemm_kernel<<<grid, 256, 0, stream>>>(Xc, Wq, Bq, Qs, Kb, Vt);
    }
    // 2) Attention: 3-way split-K, grid (32 bh, 24) = 768 WGs of 8 waves
    //    = 3 WGs/CU = 6 waves/SIMD; all WGs of a head on one XCD.
    {
        dim3 grid(BATCH * NHEAD, 24);
        attn_kernel<<<grid, 512, 0, stream>>>(Qs, Kb, Vt, Opart, MLpart);
        attn_merge_kernel<<<(NTOK * NHEAD * 4) / 256, 256, 0, stream>>>(
            Opart, MLpart, Ao);
    }
    // 3) Out projection: 128x64 tiles -> 512 WGs (2 WGs/CU)
    {
        dim3 grid(DMODEL / 64, NTOK / 128);
        proj_gemm_kernel<<<grid, 256, 0, stream>>>(Ao, Wo, Bo, d_out, flag);
    }
}